// Round 1
// baseline (896.554 us; speedup 1.0000x reference)
//
#include <hip/hip_runtime.h>
#include <math.h>

#define Dm 1024
#define Hn 16
#define HDn 64

// ---------------------------------------------------------------------------
// Generic 4096x1024x1024 fp32 GEMM: out = maybe_relu(X @ W + bias)
// layout 0: store [B,H,S,HD]   (Q, V)
// layout 1: store [B,H,HD,S]   (K transposed, for coalesced score reads)
// layout 2: store flat [B,S,D] (final output)
// Block: 256 threads, 64x64 tile, each thread 4x4, K-tile 16.
// ---------------------------------------------------------------------------
__global__ __launch_bounds__(256) void gemm_relu_kernel(
    const float* __restrict__ X, const float* __restrict__ W,
    const float* __restrict__ bias, float* __restrict__ out,
    int layout, int do_relu)
{
    __shared__ __align__(16) float sA[16][68];  // sA[k][m] (transposed)
    __shared__ __align__(16) float sB[16][68];  // sB[k][n]

    const int tid = threadIdx.x;
    const int tx = tid & 15, ty = tid >> 4;
    const int bm = blockIdx.y * 64, bn = blockIdx.x * 64;

    float acc[4][4] = {};

    const int lrow = tid >> 2;          // 0..63  (A tile row)
    const int lk4  = (tid & 3) << 2;    // 0,4,8,12
    const int wr   = tid >> 4;          // 0..15  (B tile k-row)
    const int wc4  = (tid & 15) << 2;   // 0..60

    const float* Xp = X + (bm + lrow) * Dm + lk4;
    const float* Wp = W + wr * Dm + bn + wc4;

    for (int kt = 0; kt < Dm; kt += 16) {
        float4 a4 = *(const float4*)(Xp + kt);
        float4 b4 = *(const float4*)(Wp + (size_t)kt * Dm);
        sA[lk4 + 0][lrow] = a4.x;
        sA[lk4 + 1][lrow] = a4.y;
        sA[lk4 + 2][lrow] = a4.z;
        sA[lk4 + 3][lrow] = a4.w;
        *(float4*)&sB[wr][wc4] = b4;
        __syncthreads();

        #pragma unroll
        for (int kk = 0; kk < 16; ++kk) {
            float4 av = *(const float4*)&sA[kk][ty << 2];
            float4 bv = *(const float4*)&sB[kk][tx << 2];
            float a[4] = {av.x, av.y, av.z, av.w};
            float b[4] = {bv.x, bv.y, bv.z, bv.w};
            #pragma unroll
            for (int i = 0; i < 4; ++i)
                #pragma unroll
                for (int j = 0; j < 4; ++j)
                    acc[i][j] = fmaf(a[i], b[j], acc[i][j]);
        }
        __syncthreads();
    }

    const int h = bn >> 6;  // tile width 64 == HD, so one head per N-tile
    #pragma unroll
    for (int i = 0; i < 4; ++i) {
        const int m = bm + (ty << 2) + i;
        const int b = m >> 10, s = m & 1023;
        #pragma unroll
        for (int j = 0; j < 4; ++j) {
            const int n = bn + (tx << 2) + j;
            float v = acc[i][j] + bias[n];
            if (do_relu) v = fmaxf(v, 0.0f);
            int idx;
            if (layout == 0)      idx = ((b * Hn + h) * 1024 + s) * 64 + (n & 63);
            else if (layout == 1) idx = ((b * Hn + h) * 64 + (n & 63)) * 1024 + s;
            else                  idx = m * 1024 + n;
            out[idx] = v;
        }
    }
}

// ---------------------------------------------------------------------------
// Attention: one block per (b, h, 8 query rows). Two-pass softmax with scores
// held in LDS (weight-transposed layout for broadcast b128 reads in PV).
// ---------------------------------------------------------------------------
__global__ __launch_bounds__(256) void attn_kernel(
    const float* __restrict__ Qh,   // [B,H,S,HD]
    const float* __restrict__ KT,   // [B,H,HD,S]
    const float* __restrict__ Vh,   // [B,H,S,HD]
    float* __restrict__ ctx)        // [B,S,D]
{
    __shared__ __align__(16) float sqT[64][8];       // q transposed: [d][r]
    __shared__ __align__(16) float swT[1024][8];     // weights:      [t][r]
    __shared__ float rowsum[8];
    __shared__ __align__(16) float pOut[8][8][64];   // [partition][r][hd]

    const int tid = threadIdx.x;
    const int b = blockIdx.z, h = blockIdx.y, s0 = blockIdx.x * 8;

    const float* Qp = Qh + (((b * Hn + h) * 1024) + s0) * 64;
    const float* Kp = KT + (b * Hn + h) * 64 * 1024;
    const float* Vp = Vh + (b * Hn + h) * 1024 * 64;

    // load 8 q rows, transposed
    for (int i = tid; i < 512; i += 256) {
        const int r = i >> 6, d = i & 63;
        sqT[d][r] = Qp[r * 64 + d];
    }
    __syncthreads();

    // ---- scores: thread handles keys tid, tid+256, tid+512, tid+768 ----
    float acc[4][8];
    #pragma unroll
    for (int t4 = 0; t4 < 4; ++t4)
        #pragma unroll
        for (int r = 0; r < 8; ++r) acc[t4][r] = 0.0f;

    #pragma unroll 4
    for (int d = 0; d < 64; ++d) {
        const float4 qa = *(const float4*)&sqT[d][0];
        const float4 qb = *(const float4*)&sqT[d][4];
        const float qv[8] = {qa.x, qa.y, qa.z, qa.w, qb.x, qb.y, qb.z, qb.w};
        const float* kr = Kp + d * 1024 + tid;
        const float kv[4] = {kr[0], kr[256], kr[512], kr[768]};
        #pragma unroll
        for (int t4 = 0; t4 < 4; ++t4)
            #pragma unroll
            for (int r = 0; r < 8; ++r)
                acc[t4][r] = fmaf(kv[t4], qv[r], acc[t4][r]);
    }
    const float scale = 0.03125f;  // 1/sqrt(1024)
    #pragma unroll
    for (int t4 = 0; t4 < 4; ++t4) {
        const int t = t4 * 256 + tid;
        *(float4*)&swT[t][0] = make_float4(acc[t4][0] * scale, acc[t4][1] * scale,
                                           acc[t4][2] * scale, acc[t4][3] * scale);
        *(float4*)&swT[t][4] = make_float4(acc[t4][4] * scale, acc[t4][5] * scale,
                                           acc[t4][6] * scale, acc[t4][7] * scale);
    }
    __syncthreads();

    // ---- softmax: one 32-lane group per row; exp stored, norm deferred ----
    {
        const int r = tid >> 5, l = tid & 31;
        float m = -1e30f;
        for (int t = l; t < 1024; t += 32) m = fmaxf(m, swT[t][r]);
        #pragma unroll
        for (int off = 16; off > 0; off >>= 1) m = fmaxf(m, __shfl_down(m, off, 32));
        m = __shfl(m, 0, 32);
        float sum = 0.0f;
        for (int t = l; t < 1024; t += 32) {
            const float e = __expf(swT[t][r] - m);
            swT[t][r] = e;
            sum += e;
        }
        #pragma unroll
        for (int off = 16; off > 0; off >>= 1) sum += __shfl_down(sum, off, 32);
        if (l == 0) rowsum[r] = sum;
    }
    __syncthreads();

    // ---- PV: thread (p = tid>>5) covers keys p*128..p*128+127, hd pair ----
    {
        const int hp = tid & 31, p = tid >> 5;
        float a0[8] = {}, a1[8] = {};
        for (int ti = 0; ti < 128; ++ti) {
            const int t = p * 128 + ti;
            const float4 wa = *(const float4*)&swT[t][0];
            const float4 wb = *(const float4*)&swT[t][4];
            const float w[8] = {wa.x, wa.y, wa.z, wa.w, wb.x, wb.y, wb.z, wb.w};
            const float2 vv = *(const float2*)&Vp[t * 64 + hp * 2];
            #pragma unroll
            for (int r = 0; r < 8; ++r) {
                a0[r] = fmaf(w[r], vv.x, a0[r]);
                a1[r] = fmaf(w[r], vv.y, a1[r]);
            }
        }
        #pragma unroll
        for (int r = 0; r < 8; ++r) {
            *(float2*)&pOut[p][r][hp * 2] = make_float2(a0[r], a1[r]);
        }
    }
    __syncthreads();

    // ---- reduce 8 partitions, divide by row sum, store ctx [B,S,D] ----
    for (int i = tid; i < 512; i += 256) {
        const int r = i >> 6, d = i & 63;
        float o = 0.0f;
        #pragma unroll
        for (int p2 = 0; p2 < 8; ++p2) o += pOut[p2][r][d];
        o /= rowsum[r];
        ctx[(b * 1024 + s0 + r) * 1024 + h * 64 + d] = o;
    }
}

// ---------------------------------------------------------------------------
extern "C" void kernel_launch(void* const* d_in, const int* in_sizes, int n_in,
                              void* d_out, int out_size, void* d_ws, size_t ws_size,
                              hipStream_t stream)
{
    const float* q  = (const float*)d_in[0];
    const float* k  = (const float*)d_in[1];
    const float* v  = (const float*)d_in[2];
    const float* Wq = (const float*)d_in[3];
    const float* bq = (const float*)d_in[4];
    const float* Wk = (const float*)d_in[5];
    const float* bk = (const float*)d_in[6];
    const float* Wv = (const float*)d_in[7];
    const float* bv = (const float*)d_in[8];
    const float* Wo = (const float*)d_in[9];
    const float* bo = (const float*)d_in[10];

    float* ws  = (float*)d_ws;
    float* Qh  = ws;                      // [B,H,S,HD]  16 MB
    float* KTr = ws + 4 * 1024 * 1024;    // [B,H,HD,S]  16 MB
    float* Vh  = ws + 8 * 1024 * 1024;    // [B,H,S,HD]  16 MB
    float* ctx = ws + 12 * 1024 * 1024;   // [B,S,D]     16 MB

    const dim3 gb(16, 64), tb(256);
    gemm_relu_kernel<<<gb, tb, 0, stream>>>(q, Wq, bq, Qh, 0, 1);
    gemm_relu_kernel<<<gb, tb, 0, stream>>>(k, Wk, bk, KTr, 1, 1);
    gemm_relu_kernel<<<gb, tb, 0, stream>>>(v, Wv, bv, Vh, 0, 1);

    attn_kernel<<<dim3(128, Hn, 4), 256, 0, stream>>>(Qh, KTr, Vh, ctx);

    gemm_relu_kernel<<<gb, tb, 0, stream>>>(ctx, Wo, bo, (float*)d_out, 2, 0);
}

// Round 2
// 515.160 us; speedup vs baseline: 1.7403x; 1.7403x over previous
//
#include <hip/hip_runtime.h>
#include <math.h>

#define Dm 1024
#define Hn 16
#define HDn 64

typedef __attribute__((ext_vector_type(8))) __bf16 bf16x8;
typedef __attribute__((ext_vector_type(4))) float floatx4;

__device__ __forceinline__ void async_ld16(void* lds, const void* g) {
    __builtin_amdgcn_global_load_lds(
        (const __attribute__((address_space(1))) void*)g,
        (__attribute__((address_space(3))) void*)lds,
        16, 0, 0);
}

// ---------------------------------------------------------------------------
// fp32 -> bf16 cast for q,k,v (blockIdx.y selects tensor), 8 elems/thread
// ---------------------------------------------------------------------------
__global__ __launch_bounds__(256) void cast_qkv_kernel(
    const float* __restrict__ a, const float* __restrict__ b, const float* __restrict__ c,
    __bf16* __restrict__ oa, __bf16* __restrict__ ob, __bf16* __restrict__ oc)
{
    const int lin = blockIdx.x * 256 + threadIdx.x;   // 0 .. 512K-1
    const float* src = (blockIdx.y == 0) ? a : (blockIdx.y == 1) ? b : c;
    __bf16* dst = (blockIdx.y == 0) ? oa : (blockIdx.y == 1) ? ob : oc;
    const float4 v0 = ((const float4*)src)[lin * 2];
    const float4 v1 = ((const float4*)src)[lin * 2 + 1];
    bf16x8 o;
    o[0] = (__bf16)v0.x; o[1] = (__bf16)v0.y; o[2] = (__bf16)v0.z; o[3] = (__bf16)v0.w;
    o[4] = (__bf16)v1.x; o[5] = (__bf16)v1.y; o[6] = (__bf16)v1.z; o[7] = (__bf16)v1.w;
    ((bf16x8*)dst)[lin] = o;
}

// ---------------------------------------------------------------------------
// W [k][n] fp32  ->  WT [n][k] bf16 (64x64 LDS tiles, blockIdx.z selects W)
// ---------------------------------------------------------------------------
__global__ __launch_bounds__(256) void cast_wt_kernel(
    const float* __restrict__ W0, const float* __restrict__ W1,
    const float* __restrict__ W2, const float* __restrict__ W3,
    __bf16* __restrict__ O0, __bf16* __restrict__ O1,
    __bf16* __restrict__ O2, __bf16* __restrict__ O3)
{
    __shared__ float sT[64][65];
    const int z = blockIdx.z;
    const float* W = (z == 0) ? W0 : (z == 1) ? W1 : (z == 2) ? W2 : W3;
    __bf16* O = (z == 0) ? O0 : (z == 1) ? O1 : (z == 2) ? O2 : O3;

    const int tid = threadIdx.x;
    const int bi = blockIdx.y * 64;   // k block
    const int bj = blockIdx.x * 64;   // n block
    const int colr = tid & 63, rowg = tid >> 6;

    #pragma unroll
    for (int i = 0; i < 16; ++i) {
        const int kk = i * 4 + rowg;
        sT[kk][colr] = W[(size_t)(bi + kk) * Dm + bj + colr];
    }
    __syncthreads();
    #pragma unroll
    for (int i = 0; i < 16; ++i) {
        const int rn = i * 4 + rowg;
        O[(size_t)(bj + rn) * Dm + bi + colr] = (__bf16)sT[colr][rn];
    }
}

// ---------------------------------------------------------------------------
// bf16 MFMA GEMM: out = maybe_relu(X @ WT^T + bias), M=4096, N=K=1024.
// X [M][K] bf16 row-major; WT [N][K] bf16 (pre-transposed W).
// 128(M) x 64(N) tile / block; 256 thr = 4 waves, wave = 64x32 (4x2 frags).
// global_load_lds width-16 staging, XOR chunk swizzle for conflict-free
// ds_read_b128 fragment loads. fp32 accum in MFMA.
// layout 0: [B,H,S,HD]; 1: [B,H,HD,S]; 2: flat [M][N].
// ---------------------------------------------------------------------------
__global__ __launch_bounds__(256) void gemm_bf16_kernel(
    const __bf16* __restrict__ Xb, const __bf16* __restrict__ WTb,
    const float* __restrict__ bias, float* __restrict__ out,
    int layout, int do_relu)
{
    __shared__ __align__(16) __bf16 sA[128 * 32];  // [r][chunk^(r&3) swizzled]
    __shared__ __align__(16) __bf16 sB[64 * 32];

    const int tid = threadIdx.x;
    const int bm = blockIdx.y * 128, bn = blockIdx.x * 64;
    const int lane = tid & 63;
    const int wave = tid >> 6;
    const int wm = (wave & 1) * 64;    // wave row offset in tile
    const int wn = (wave >> 1) * 32;   // wave col offset in tile
    const int l15 = lane & 15, quad = lane >> 4;

    floatx4 acc[4][2];
    #pragma unroll
    for (int mi = 0; mi < 4; ++mi)
        #pragma unroll
        for (int ni = 0; ni < 2; ++ni)
            acc[mi][ni] = (floatx4){0.f, 0.f, 0.f, 0.f};

    // staging addresses (A: 2 chunks/thread, B: 1 chunk/thread)
    const int ciA0 = tid,      rA0 = ciA0 >> 2, qA0 = (ciA0 & 3) ^ (rA0 & 3);
    const int ciA1 = 256 + tid, rA1 = ciA1 >> 2, qA1 = (ciA1 & 3) ^ (rA1 & 3);
    const int rB = tid >> 2,    qB = (tid & 3) ^ (rB & 3);
    const __bf16* gA0 = Xb + (size_t)(bm + rA0) * Dm + qA0 * 8;
    const __bf16* gA1 = Xb + (size_t)(bm + rA1) * Dm + qA1 * 8;
    const __bf16* gB  = WTb + (size_t)(bn + rB) * Dm + qB * 8;
    char* lA0 = (char*)sA + (tid & 192) * 16;
    char* lA1 = (char*)sA + (256 + (tid & 192)) * 16;
    char* lB  = (char*)sB + (tid & 192) * 16;

    // fragment LDS addresses (invariant across K loop)
    const __bf16* fA[4];
    const __bf16* fB[2];
    #pragma unroll
    for (int mi = 0; mi < 4; ++mi) {
        const int r = wm + mi * 16 + l15;
        fA[mi] = sA + r * 32 + ((quad ^ (r & 3)) * 8);
    }
    #pragma unroll
    for (int ni = 0; ni < 2; ++ni) {
        const int r = wn + ni * 16 + l15;
        fB[ni] = sB + r * 32 + ((quad ^ (r & 3)) * 8);
    }

    for (int kt = 0; kt < Dm; kt += 32) {
        async_ld16(lA0, gA0 + kt);
        async_ld16(lA1, gA1 + kt);
        async_ld16(lB,  gB  + kt);
        __syncthreads();

        bf16x8 af[4], bfr[2];
        #pragma unroll
        for (int mi = 0; mi < 4; ++mi) af[mi] = *(const bf16x8*)fA[mi];
        #pragma unroll
        for (int ni = 0; ni < 2; ++ni) bfr[ni] = *(const bf16x8*)fB[ni];
        #pragma unroll
        for (int mi = 0; mi < 4; ++mi)
            #pragma unroll
            for (int ni = 0; ni < 2; ++ni)
                acc[mi][ni] = __builtin_amdgcn_mfma_f32_16x16x32_bf16(
                    af[mi], bfr[ni], acc[mi][ni], 0, 0, 0);
        __syncthreads();
    }

    // epilogue: C/D layout col=lane&15, row=quad*4+reg
    #pragma unroll
    for (int mi = 0; mi < 4; ++mi) {
        #pragma unroll
        for (int ni = 0; ni < 2; ++ni) {
            const int n = bn + wn + ni * 16 + l15;
            const float bv = bias[n];
            const int h = n >> 6, d = n & 63;
            #pragma unroll
            for (int reg = 0; reg < 4; ++reg) {
                const int m = bm + wm + mi * 16 + quad * 4 + reg;
                const int b = m >> 10, s = m & 1023;
                float v = acc[mi][ni][reg] + bv;
                if (do_relu) v = fmaxf(v, 0.0f);
                size_t idx;
                if (layout == 0)      idx = ((size_t)(b * Hn + h) * 1024 + s) * 64 + d;
                else if (layout == 1) idx = ((size_t)(b * Hn + h) * 64 + d) * 1024 + s;
                else                  idx = (size_t)m * 1024 + n;
                out[idx] = v;
            }
        }
    }
}

// ---------------------------------------------------------------------------
// Attention (fp32, unchanged except bf16 ctx store)
// ---------------------------------------------------------------------------
__global__ __launch_bounds__(256) void attn_kernel(
    const float* __restrict__ Qh,   // [B,H,S,HD]
    const float* __restrict__ KT,   // [B,H,HD,S]
    const float* __restrict__ Vh,   // [B,H,S,HD]
    __bf16* __restrict__ ctx)       // [B,S,D] bf16
{
    __shared__ __align__(16) float sqT[64][8];
    __shared__ __align__(16) float swT[1024][8];
    __shared__ float rowsum[8];
    __shared__ __align__(16) float pOut[8][8][64];

    const int tid = threadIdx.x;
    const int b = blockIdx.z, h = blockIdx.y, s0 = blockIdx.x * 8;

    const float* Qp = Qh + (((b * Hn + h) * 1024) + s0) * 64;
    const float* Kp = KT + (b * Hn + h) * 64 * 1024;
    const float* Vp = Vh + (b * Hn + h) * 1024 * 64;

    for (int i = tid; i < 512; i += 256) {
        const int r = i >> 6, d = i & 63;
        sqT[d][r] = Qp[r * 64 + d];
    }
    __syncthreads();

    float acc[4][8];
    #pragma unroll
    for (int t4 = 0; t4 < 4; ++t4)
        #pragma unroll
        for (int r = 0; r < 8; ++r) acc[t4][r] = 0.0f;

    #pragma unroll 4
    for (int d = 0; d < 64; ++d) {
        const float4 qa = *(const float4*)&sqT[d][0];
        const float4 qb = *(const float4*)&sqT[d][4];
        const float qv[8] = {qa.x, qa.y, qa.z, qa.w, qb.x, qb.y, qb.z, qb.w};
        const float* kr = Kp + d * 1024 + tid;
        const float kv[4] = {kr[0], kr[256], kr[512], kr[768]};
        #pragma unroll
        for (int t4 = 0; t4 < 4; ++t4)
            #pragma unroll
            for (int r = 0; r < 8; ++r)
                acc[t4][r] = fmaf(kv[t4], qv[r], acc[t4][r]);
    }
    const float scale = 0.03125f;
    #pragma unroll
    for (int t4 = 0; t4 < 4; ++t4) {
        const int t = t4 * 256 + tid;
        *(float4*)&swT[t][0] = make_float4(acc[t4][0] * scale, acc[t4][1] * scale,
                                           acc[t4][2] * scale, acc[t4][3] * scale);
        *(float4*)&swT[t][4] = make_float4(acc[t4][4] * scale, acc[t4][5] * scale,
                                           acc[t4][6] * scale, acc[t4][7] * scale);
    }
    __syncthreads();

    {
        const int r = tid >> 5, l = tid & 31;
        float m = -1e30f;
        for (int t = l; t < 1024; t += 32) m = fmaxf(m, swT[t][r]);
        #pragma unroll
        for (int off = 16; off > 0; off >>= 1) m = fmaxf(m, __shfl_down(m, off, 32));
        m = __shfl(m, 0, 32);
        float sum = 0.0f;
        for (int t = l; t < 1024; t += 32) {
            const float e = __expf(swT[t][r] - m);
            swT[t][r] = e;
            sum += e;
        }
        #pragma unroll
        for (int off = 16; off > 0; off >>= 1) sum += __shfl_down(sum, off, 32);
        if (l == 0) rowsum[r] = sum;
    }
    __syncthreads();

    {
        const int hp = tid & 31, p = tid >> 5;
        float a0[8] = {}, a1[8] = {};
        for (int ti = 0; ti < 128; ++ti) {
            const int t = p * 128 + ti;
            const float4 wa = *(const float4*)&swT[t][0];
            const float4 wb = *(const float4*)&swT[t][4];
            const float w[8] = {wa.x, wa.y, wa.z, wa.w, wb.x, wb.y, wb.z, wb.w};
            const float2 vv = *(const float2*)&Vp[t * 64 + hp * 2];
            #pragma unroll
            for (int r = 0; r < 8; ++r) {
                a0[r] = fmaf(w[r], vv.x, a0[r]);
                a1[r] = fmaf(w[r], vv.y, a1[r]);
            }
        }
        #pragma unroll
        for (int r = 0; r < 8; ++r) {
            *(float2*)&pOut[p][r][hp * 2] = make_float2(a0[r], a1[r]);
        }
    }
    __syncthreads();

    for (int i = tid; i < 512; i += 256) {
        const int r = i >> 6, d = i & 63;
        float o = 0.0f;
        #pragma unroll
        for (int p2 = 0; p2 < 8; ++p2) o += pOut[p2][r][d];
        o /= rowsum[r];
        ctx[(size_t)(b * 1024 + s0 + r) * 1024 + h * 64 + d] = (__bf16)o;
    }
}

// ---------------------------------------------------------------------------
extern "C" void kernel_launch(void* const* d_in, const int* in_sizes, int n_in,
                              void* d_out, int out_size, void* d_ws, size_t ws_size,
                              hipStream_t stream)
{
    const float* q  = (const float*)d_in[0];
    const float* k  = (const float*)d_in[1];
    const float* v  = (const float*)d_in[2];
    const float* Wq = (const float*)d_in[3];
    const float* bq = (const float*)d_in[4];
    const float* Wk = (const float*)d_in[5];
    const float* bk = (const float*)d_in[6];
    const float* Wv = (const float*)d_in[7];
    const float* bv = (const float*)d_in[8];
    const float* Wo = (const float*)d_in[9];
    const float* bo = (const float*)d_in[10];

    float* ws = (float*)d_ws;
    float*  Qh  = ws;                        // 16 MB fp32 [B,H,S,HD]
    float*  KTr = ws + 4  * 1024 * 1024;     // 16 MB fp32 [B,H,HD,S]
    float*  Vh  = ws + 8  * 1024 * 1024;     // 16 MB fp32 [B,H,S,HD]
    __bf16* qb  = (__bf16*)(ws + 12 * 1024 * 1024);  // 8 MB bf16 [4096][1024]
    __bf16* kb  = (__bf16*)(ws + 14 * 1024 * 1024);
    __bf16* vb  = (__bf16*)(ws + 16 * 1024 * 1024);
    __bf16* WTq = (__bf16*)(ws + 18 * 1024 * 1024);        // 2 MB each [N][K]
    __bf16* WTk = (__bf16*)(ws + 18 * 1024 * 1024 + 512 * 1024);
    __bf16* WTv = (__bf16*)(ws + 19 * 1024 * 1024);
    __bf16* WTo = (__bf16*)(ws + 19 * 1024 * 1024 + 512 * 1024);
    __bf16* ctx = (__bf16*)(ws + 20 * 1024 * 1024);  // 8 MB bf16 [4096][1024]

    cast_qkv_kernel<<<dim3(2048, 3), 256, 0, stream>>>(q, k, v, qb, kb, vb);
    cast_wt_kernel<<<dim3(16, 16, 4), 256, 0, stream>>>(Wq, Wk, Wv, Wo,
                                                        WTq, WTk, WTv, WTo);

    const dim3 gg(16, 32), tb(256);
    gemm_bf16_kernel<<<gg, tb, 0, stream>>>(qb, WTq, bq, Qh, 0, 1);
    gemm_bf16_kernel<<<gg, tb, 0, stream>>>(kb, WTk, bk, KTr, 1, 1);
    gemm_bf16_kernel<<<gg, tb, 0, stream>>>(vb, WTv, bv, Vh, 0, 1);

    attn_kernel<<<dim3(128, Hn, 4), 256, 0, stream>>>(Qh, KTr, Vh, ctx);

    gemm_bf16_kernel<<<gg, tb, 0, stream>>>(ctx, WTo, bo, (float*)d_out, 2, 0);
}

// Round 3
// 276.509 us; speedup vs baseline: 3.2424x; 1.8631x over previous
//
#include <hip/hip_runtime.h>
#include <math.h>

#define Dm 1024
#define Hn 16
#define HDn 64
#define Sn 1024

typedef __attribute__((ext_vector_type(8))) __bf16 bf16x8;
typedef __attribute__((ext_vector_type(4))) float floatx4;

__device__ __forceinline__ void async_ld16(void* lds, const void* g) {
    __builtin_amdgcn_global_load_lds(
        (const __attribute__((address_space(1))) void*)g,
        (__attribute__((address_space(3))) void*)lds,
        16, 0, 0);
}

// ---------------------------------------------------------------------------
// fp32 -> bf16 cast for q,k,v (blockIdx.y selects tensor), 8 elems/thread
// ---------------------------------------------------------------------------
__global__ __launch_bounds__(256) void cast_qkv_kernel(
    const float* __restrict__ a, const float* __restrict__ b, const float* __restrict__ c,
    __bf16* __restrict__ oa, __bf16* __restrict__ ob, __bf16* __restrict__ oc)
{
    const int lin = blockIdx.x * 256 + threadIdx.x;
    const float* src = (blockIdx.y == 0) ? a : (blockIdx.y == 1) ? b : c;
    __bf16* dst = (blockIdx.y == 0) ? oa : (blockIdx.y == 1) ? ob : oc;
    const float4 v0 = ((const float4*)src)[lin * 2];
    const float4 v1 = ((const float4*)src)[lin * 2 + 1];
    bf16x8 o;
    o[0] = (__bf16)v0.x; o[1] = (__bf16)v0.y; o[2] = (__bf16)v0.z; o[3] = (__bf16)v0.w;
    o[4] = (__bf16)v1.x; o[5] = (__bf16)v1.y; o[6] = (__bf16)v1.z; o[7] = (__bf16)v1.w;
    ((bf16x8*)dst)[lin] = o;
}

// ---------------------------------------------------------------------------
// W [k][n] fp32  ->  WT [n][k] bf16
// ---------------------------------------------------------------------------
__global__ __launch_bounds__(256) void cast_wt_kernel(
    const float* __restrict__ W0, const float* __restrict__ W1,
    const float* __restrict__ W2, const float* __restrict__ W3,
    __bf16* __restrict__ O0, __bf16* __restrict__ O1,
    __bf16* __restrict__ O2, __bf16* __restrict__ O3)
{
    __shared__ float sT[64][65];
    const int z = blockIdx.z;
    const float* W = (z == 0) ? W0 : (z == 1) ? W1 : (z == 2) ? W2 : W3;
    __bf16* O = (z == 0) ? O0 : (z == 1) ? O1 : (z == 2) ? O2 : O3;

    const int tid = threadIdx.x;
    const int bi = blockIdx.y * 64, bj = blockIdx.x * 64;
    const int colr = tid & 63, rowg = tid >> 6;

    #pragma unroll
    for (int i = 0; i < 16; ++i) {
        const int kk = i * 4 + rowg;
        sT[kk][colr] = W[(size_t)(bi + kk) * Dm + bj + colr];
    }
    __syncthreads();
    #pragma unroll
    for (int i = 0; i < 16; ++i) {
        const int rn = i * 4 + rowg;
        O[(size_t)(bj + rn) * Dm + bi + colr] = (__bf16)sT[colr][rn];
    }
}

// ---------------------------------------------------------------------------
// bf16 MFMA GEMM: out = maybe_relu(X @ WT^T + bias), M=4096, N=K=1024.
// layout 0: bf16 [B,H,S,HD]; 1: bf16 [B,H,HD,S]; 2: bf16 flat; 3: fp32 flat.
// ---------------------------------------------------------------------------
__global__ __launch_bounds__(256) void gemm_bf16_kernel(
    const __bf16* __restrict__ Xb, const __bf16* __restrict__ WTb,
    const float* __restrict__ bias, void* __restrict__ outp,
    int layout, int do_relu)
{
    __shared__ __align__(16) __bf16 sA[128 * 32];
    __shared__ __align__(16) __bf16 sB[64 * 32];

    const int tid = threadIdx.x;
    const int bm = blockIdx.y * 128, bn = blockIdx.x * 64;
    const int lane = tid & 63;
    const int wave = tid >> 6;
    const int wm = (wave & 1) * 64;
    const int wn = (wave >> 1) * 32;
    const int l15 = lane & 15, quad = lane >> 4;

    floatx4 acc[4][2];
    #pragma unroll
    for (int mi = 0; mi < 4; ++mi)
        #pragma unroll
        for (int ni = 0; ni < 2; ++ni)
            acc[mi][ni] = (floatx4){0.f, 0.f, 0.f, 0.f};

    const int ciA0 = tid,       rA0 = ciA0 >> 2, qA0 = (ciA0 & 3) ^ (rA0 & 3);
    const int ciA1 = 256 + tid, rA1 = ciA1 >> 2, qA1 = (ciA1 & 3) ^ (rA1 & 3);
    const int rB = tid >> 2,    qB = (tid & 3) ^ (rB & 3);
    const __bf16* gA0 = Xb + (size_t)(bm + rA0) * Dm + qA0 * 8;
    const __bf16* gA1 = Xb + (size_t)(bm + rA1) * Dm + qA1 * 8;
    const __bf16* gB  = WTb + (size_t)(bn + rB) * Dm + qB * 8;
    char* lA0 = (char*)sA + (tid & 192) * 16;
    char* lA1 = (char*)sA + (256 + (tid & 192)) * 16;
    char* lB  = (char*)sB + (tid & 192) * 16;

    const __bf16* fA[4];
    const __bf16* fB[2];
    #pragma unroll
    for (int mi = 0; mi < 4; ++mi) {
        const int r = wm + mi * 16 + l15;
        fA[mi] = sA + r * 32 + ((quad ^ (r & 3)) * 8);
    }
    #pragma unroll
    for (int ni = 0; ni < 2; ++ni) {
        const int r = wn + ni * 16 + l15;
        fB[ni] = sB + r * 32 + ((quad ^ (r & 3)) * 8);
    }

    for (int kt = 0; kt < Dm; kt += 32) {
        async_ld16(lA0, gA0 + kt);
        async_ld16(lA1, gA1 + kt);
        async_ld16(lB,  gB  + kt);
        __syncthreads();

        bf16x8 af[4], bfr[2];
        #pragma unroll
        for (int mi = 0; mi < 4; ++mi) af[mi] = *(const bf16x8*)fA[mi];
        #pragma unroll
        for (int ni = 0; ni < 2; ++ni) bfr[ni] = *(const bf16x8*)fB[ni];
        #pragma unroll
        for (int mi = 0; mi < 4; ++mi)
            #pragma unroll
            for (int ni = 0; ni < 2; ++ni)
                acc[mi][ni] = __builtin_amdgcn_mfma_f32_16x16x32_bf16(
                    af[mi], bfr[ni], acc[mi][ni], 0, 0, 0);
        __syncthreads();
    }

    #pragma unroll
    for (int mi = 0; mi < 4; ++mi) {
        #pragma unroll
        for (int ni = 0; ni < 2; ++ni) {
            const int n = bn + wn + ni * 16 + l15;
            const float bv = bias[n];
            const int h = n >> 6, d = n & 63;
            #pragma unroll
            for (int reg = 0; reg < 4; ++reg) {
                const int m = bm + wm + mi * 16 + quad * 4 + reg;
                const int b = m >> 10, s = m & 1023;
                float v = acc[mi][ni][reg] + bv;
                if (do_relu) v = fmaxf(v, 0.0f);
                if (layout == 0)
                    ((__bf16*)outp)[((size_t)(b * Hn + h) * 1024 + s) * 64 + d] = (__bf16)v;
                else if (layout == 1)
                    ((__bf16*)outp)[((size_t)(b * Hn + h) * 64 + d) * 1024 + s] = (__bf16)v;
                else if (layout == 2)
                    ((__bf16*)outp)[(size_t)m * 1024 + n] = (__bf16)v;
                else
                    ((float*)outp)[(size_t)m * 1024 + n] = v;
            }
        }
    }
}

// ---------------------------------------------------------------------------
// Flash attention, bf16 MFMA. Block = (b, h, 128 q rows); wave = 32 q rows.
// K-tiles of 64 keys, double-buffered LDS staging.
// ---------------------------------------------------------------------------
__global__ __launch_bounds__(256, 2) void flash_attn_kernel(
    const __bf16* __restrict__ Qh,  // [B,H,S,HD]
    const __bf16* __restrict__ Kh,  // [B,H,S,HD]
    const __bf16* __restrict__ Vt,  // [B,H,HD,S]
    __bf16* __restrict__ ctx)       // [B,S,D]
{
    __shared__ __align__(16) char sKV[2][16384];   // per buf: K 8KB | V 8KB
    __shared__ __align__(16) __bf16 sP[4][32 * 64];

    const int tid = threadIdx.x;
    const int wave = tid >> 6, lane = tid & 63;
    const int l15 = lane & 15, quad = lane >> 4;
    const int b = blockIdx.z, h = blockIdx.y;
    const int bh = b * Hn + h;
    const int qb = blockIdx.x * 128 + wave * 32;

    // Q fragments (A-operand), held for the whole kernel
    bf16x8 aQ[2][2];
    #pragma unroll
    for (int mi = 0; mi < 2; ++mi)
        #pragma unroll
        for (int ks = 0; ks < 2; ++ks)
            aQ[mi][ks] = *(const bf16x8*)(Qh +
                (size_t)(bh * Sn + qb + mi * 16 + l15) * 64 + ks * 32 + quad * 8);

    // staging: slots s0 = tid (rows 0..31), s1 = 256+tid (rows 32..63)
    const int s0 = tid, s1 = tid + 256;
    const int r0 = s0 >> 3, q0c = (s0 & 7) ^ (r0 & 7);
    const int r1 = s1 >> 3, q1c = (s1 & 7) ^ (r1 & 7);
    const __bf16* gK0 = Kh + (size_t)(bh * Sn + r0) * 64 + q0c * 8;
    const __bf16* gK1 = Kh + (size_t)(bh * Sn + r1) * 64 + q1c * 8;
    const __bf16* gV0 = Vt + (size_t)(bh * 64 + r0) * Sn + q0c * 8;
    const __bf16* gV1 = Vt + (size_t)(bh * 64 + r1) * Sn + q1c * 8;
    const int wofs = (tid & 192) * 16;

    float mrow[2][4], lrow[2][4];
    floatx4 oacc[2][4];
    #pragma unroll
    for (int mi = 0; mi < 2; ++mi)
        #pragma unroll
        for (int r = 0; r < 4; ++r) { mrow[mi][r] = -3.0e38f; lrow[mi][r] = 0.0f; }
    #pragma unroll
    for (int mi = 0; mi < 2; ++mi)
        #pragma unroll
        for (int nf = 0; nf < 4; ++nf)
            oacc[mi][nf] = (floatx4){0.f, 0.f, 0.f, 0.f};

    const float c = 0.0450842200f;  // (1/32) * log2(e)
    __bf16* sPw = sP[wave];

    // prefetch tile 0 into buf 0
    {
        char* bK = sKV[0];
        char* bV = sKV[0] + 8192;
        async_ld16(bK + wofs,        gK0);
        async_ld16(bK + 4096 + wofs, gK1);
        async_ld16(bV + wofs,        gV0);
        async_ld16(bV + 4096 + wofs, gV1);
    }

    int cur = 0;
    for (int it = 0; it < 16; ++it) {
        __syncthreads();   // staged loads drained (vmcnt) + all waves ready

        if (it + 1 < 16) {
            const int t0n = (it + 1) * 64;
            char* bK = sKV[cur ^ 1];
            char* bV = sKV[cur ^ 1] + 8192;
            async_ld16(bK + wofs,        gK0 + (size_t)t0n * 64);
            async_ld16(bK + 4096 + wofs, gK1 + (size_t)t0n * 64);
            async_ld16(bV + wofs,        gV0 + t0n);
            async_ld16(bV + 4096 + wofs, gV1 + t0n);
        }

        const __bf16* sK = (const __bf16*)sKV[cur];
        const __bf16* sV = (const __bf16*)(sKV[cur] + 8192);

        // ---- QK^T ----
        floatx4 sc[2][4];
        #pragma unroll
        for (int mi = 0; mi < 2; ++mi)
            #pragma unroll
            for (int nf = 0; nf < 4; ++nf)
                sc[mi][nf] = (floatx4){0.f, 0.f, 0.f, 0.f};
        #pragma unroll
        for (int ks = 0; ks < 2; ++ks) {
            bf16x8 bK[4];
            #pragma unroll
            for (int nf = 0; nf < 4; ++nf) {
                const int n = nf * 16 + l15;
                bK[nf] = *(const bf16x8*)(sK + (n * 8 + (((ks << 2) + quad) ^ (n & 7))) * 8);
            }
            #pragma unroll
            for (int mi = 0; mi < 2; ++mi)
                #pragma unroll
                for (int nf = 0; nf < 4; ++nf)
                    sc[mi][nf] = __builtin_amdgcn_mfma_f32_16x16x32_bf16(
                        aQ[mi][ks], bK[nf], sc[mi][nf], 0, 0, 0);
        }

        // ---- online softmax ----
        float tmax[2][4];
        #pragma unroll
        for (int mi = 0; mi < 2; ++mi)
            #pragma unroll
            for (int r = 0; r < 4; ++r)
                tmax[mi][r] = fmaxf(fmaxf(sc[mi][0][r], sc[mi][1][r]),
                                    fmaxf(sc[mi][2][r], sc[mi][3][r]));
        #pragma unroll
        for (int step = 1; step <= 8; step <<= 1)
            #pragma unroll
            for (int mi = 0; mi < 2; ++mi)
                #pragma unroll
                for (int r = 0; r < 4; ++r)
                    tmax[mi][r] = fmaxf(tmax[mi][r], __shfl_xor(tmax[mi][r], step, 64));

        float alpha[2][4];
        #pragma unroll
        for (int mi = 0; mi < 2; ++mi)
            #pragma unroll
            for (int r = 0; r < 4; ++r) {
                const float Mn = fmaxf(mrow[mi][r], tmax[mi][r]);
                alpha[mi][r] = exp2f((mrow[mi][r] - Mn) * c);
                mrow[mi][r] = Mn;
                lrow[mi][r] *= alpha[mi][r];
            }
        #pragma unroll
        for (int mi = 0; mi < 2; ++mi)
            #pragma unroll
            for (int nf = 0; nf < 4; ++nf)
                #pragma unroll
                for (int r = 0; r < 4; ++r)
                    oacc[mi][nf][r] *= alpha[mi][r];

        float rsum[2][4] = {};
        #pragma unroll
        for (int mi = 0; mi < 2; ++mi)
            #pragma unroll
            for (int nf = 0; nf < 4; ++nf) {
                const int t = nf * 16 + l15;
                #pragma unroll
                for (int r = 0; r < 4; ++r) {
                    const float p = exp2f((sc[mi][nf][r] - mrow[mi][r]) * c);
                    const __bf16 pb = (__bf16)p;
                    rsum[mi][r] += (float)pb;
                    const int rr = mi * 16 + quad * 4 + r;
                    sPw[(rr * 8 + ((t >> 3) ^ (rr & 7))) * 8 + (t & 7)] = pb;
                }
            }
        #pragma unroll
        for (int step = 1; step <= 8; step <<= 1)
            #pragma unroll
            for (int mi = 0; mi < 2; ++mi)
                #pragma unroll
                for (int r = 0; r < 4; ++r)
                    rsum[mi][r] += __shfl_xor(rsum[mi][r], step, 64);
        #pragma unroll
        for (int mi = 0; mi < 2; ++mi)
            #pragma unroll
            for (int r = 0; r < 4; ++r)
                lrow[mi][r] += rsum[mi][r];

        // ---- PV (sP is wave-private: no barrier, lgkmcnt only) ----
        #pragma unroll
        for (int ks = 0; ks < 2; ++ks) {
            bf16x8 aP[2], bV[4];
            #pragma unroll
            for (int mi = 0; mi < 2; ++mi) {
                const int r = mi * 16 + l15;
                aP[mi] = *(const bf16x8*)(sPw + (r * 8 + (((ks << 2) + quad) ^ (r & 7))) * 8);
            }
            #pragma unroll
            for (int nf = 0; nf < 4; ++nf) {
                const int n = nf * 16 + l15;
                bV[nf] = *(const bf16x8*)(sV + (n * 8 + (((ks << 2) + quad) ^ (n & 7))) * 8);
            }
            #pragma unroll
            for (int mi = 0; mi < 2; ++mi)
                #pragma unroll
                for (int nf = 0; nf < 4; ++nf)
                    oacc[mi][nf] = __builtin_amdgcn_mfma_f32_16x16x32_bf16(
                        aP[mi], bV[nf], oacc[mi][nf], 0, 0, 0);
        }

        cur ^= 1;
    }

    // ---- epilogue: normalize, store ctx bf16 [B,S,D] ----
    float rl[2][4];
    #pragma unroll
    for (int mi = 0; mi < 2; ++mi)
        #pragma unroll
        for (int r = 0; r < 4; ++r)
            rl[mi][r] = 1.0f / lrow[mi][r];
    #pragma unroll
    for (int mi = 0; mi < 2; ++mi)
        #pragma unroll
        for (int nf = 0; nf < 4; ++nf) {
            const int d = h * 64 + nf * 16 + l15;
            #pragma unroll
            for (int r = 0; r < 4; ++r) {
                const int s = qb + mi * 16 + quad * 4 + r;
                ctx[(size_t)(b * Sn + s) * Dm + d] = (__bf16)(oacc[mi][nf][r] * rl[mi][r]);
            }
        }
}

// ---------------------------------------------------------------------------
extern "C" void kernel_launch(void* const* d_in, const int* in_sizes, int n_in,
                              void* d_out, int out_size, void* d_ws, size_t ws_size,
                              hipStream_t stream)
{
    const float* q  = (const float*)d_in[0];
    const float* k  = (const float*)d_in[1];
    const float* v  = (const float*)d_in[2];
    const float* Wq = (const float*)d_in[3];
    const float* bq = (const float*)d_in[4];
    const float* Wk = (const float*)d_in[5];
    const float* bk = (const float*)d_in[6];
    const float* Wv = (const float*)d_in[7];
    const float* bv = (const float*)d_in[8];
    const float* Wo = (const float*)d_in[9];
    const float* bo = (const float*)d_in[10];

    char* ws = (char*)d_ws;
    const size_t MB = 1024 * 1024;
    __bf16* qb_ = (__bf16*)(ws);            // 8 MB [4096][1024]
    __bf16* kb_ = (__bf16*)(ws + 8 * MB);
    __bf16* vb_ = (__bf16*)(ws + 16 * MB);
    __bf16* WTq = (__bf16*)(ws + 24 * MB);  // 2 MB each [N][K]
    __bf16* WTk = (__bf16*)(ws + 26 * MB);
    __bf16* WTv = (__bf16*)(ws + 28 * MB);
    __bf16* WTo = (__bf16*)(ws + 30 * MB);
    __bf16* Qh  = (__bf16*)(ws + 32 * MB);  // 8 MB [B,H,S,HD]
    __bf16* Kh  = (__bf16*)(ws + 40 * MB);  // 8 MB [B,H,S,HD]
    __bf16* Vt  = (__bf16*)(ws + 48 * MB);  // 8 MB [B,H,HD,S]
    __bf16* ctx = (__bf16*)(ws + 56 * MB);  // 8 MB [B,S,D]

    cast_qkv_kernel<<<dim3(2048, 3), 256, 0, stream>>>(q, k, v, qb_, kb_, vb_);
    cast_wt_kernel<<<dim3(16, 16, 4), 256, 0, stream>>>(Wq, Wk, Wv, Wo,
                                                        WTq, WTk, WTv, WTo);

    const dim3 gg(16, 32), tb(256);
    gemm_bf16_kernel<<<gg, tb, 0, stream>>>(qb_, WTq, bq, Qh, 0, 1);
    gemm_bf16_kernel<<<gg, tb, 0, stream>>>(kb_, WTk, bk, Kh, 0, 1);
    gemm_bf16_kernel<<<gg, tb, 0, stream>>>(vb_, WTv, bv, Vt, 1, 1);

    flash_attn_kernel<<<dim3(8, Hn, 4), 256, 0, stream>>>(Qh, Kh, Vt, ctx);

    gemm_bf16_kernel<<<gg, tb, 0, stream>>>(ctx, WTo, bo, d_out, 3, 0);
}

// Round 5
// 247.819 us; speedup vs baseline: 3.6178x; 1.1158x over previous
//
#include <hip/hip_runtime.h>
#include <math.h>

#define Dm 1024
#define Hn 16
#define HDn 64
#define Sn 1024

typedef __attribute__((ext_vector_type(8))) __bf16 bf16x8;
typedef __attribute__((ext_vector_type(4))) float floatx4;

__device__ __forceinline__ void async_ld16(void* lds, const void* g) {
    __builtin_amdgcn_global_load_lds(
        (const __attribute__((address_space(1))) void*)g,
        (__attribute__((address_space(3))) void*)lds,
        16, 0, 0);
}

// ---------------------------------------------------------------------------
// fp32 -> bf16 cast for q,k,v (blockIdx.y selects tensor), 8 elems/thread
// ---------------------------------------------------------------------------
__global__ __launch_bounds__(256) void cast_qkv_kernel(
    const float* __restrict__ a, const float* __restrict__ b, const float* __restrict__ c,
    __bf16* __restrict__ oa, __bf16* __restrict__ ob, __bf16* __restrict__ oc)
{
    const int lin = blockIdx.x * 256 + threadIdx.x;
    const float* src = (blockIdx.y == 0) ? a : (blockIdx.y == 1) ? b : c;
    __bf16* dst = (blockIdx.y == 0) ? oa : (blockIdx.y == 1) ? ob : oc;
    const float4 v0 = ((const float4*)src)[lin * 2];
    const float4 v1 = ((const float4*)src)[lin * 2 + 1];
    bf16x8 o;
    o[0] = (__bf16)v0.x; o[1] = (__bf16)v0.y; o[2] = (__bf16)v0.z; o[3] = (__bf16)v0.w;
    o[4] = (__bf16)v1.x; o[5] = (__bf16)v1.y; o[6] = (__bf16)v1.z; o[7] = (__bf16)v1.w;
    ((bf16x8*)dst)[lin] = o;
}

// ---------------------------------------------------------------------------
// W [k][n] fp32  ->  WT [n][k] bf16
// ---------------------------------------------------------------------------
__global__ __launch_bounds__(256) void cast_wt_kernel(
    const float* __restrict__ W0, const float* __restrict__ W1,
    const float* __restrict__ W2, const float* __restrict__ W3,
    __bf16* __restrict__ O0, __bf16* __restrict__ O1,
    __bf16* __restrict__ O2, __bf16* __restrict__ O3)
{
    __shared__ float sT[64][65];
    const int z = blockIdx.z;
    const float* W = (z == 0) ? W0 : (z == 1) ? W1 : (z == 2) ? W2 : W3;
    __bf16* O = (z == 0) ? O0 : (z == 1) ? O1 : (z == 2) ? O2 : O3;

    const int tid = threadIdx.x;
    const int bi = blockIdx.y * 64, bj = blockIdx.x * 64;
    const int colr = tid & 63, rowg = tid >> 6;

    #pragma unroll
    for (int i = 0; i < 16; ++i) {
        const int kk = i * 4 + rowg;
        sT[kk][colr] = W[(size_t)(bi + kk) * Dm + bj + colr];
    }
    __syncthreads();
    #pragma unroll
    for (int i = 0; i < 16; ++i) {
        const int rn = i * 4 + rowg;
        O[(size_t)(bj + rn) * Dm + bi + colr] = (__bf16)sT[colr][rn];
    }
}

// ---------------------------------------------------------------------------
// bf16 MFMA GEMM: out = maybe_relu(X @ WT^T + bias) * escale.
// layout 0: bf16 [B,H,S,HD]; 1: bf16 [B,H,HD,S]; 3: fp32 flat.
// ---------------------------------------------------------------------------
__global__ __launch_bounds__(256) void gemm_bf16_kernel(
    const __bf16* __restrict__ Xb, const __bf16* __restrict__ WTb,
    const float* __restrict__ bias, void* __restrict__ outp,
    int layout, int do_relu, float escale)
{
    __shared__ __align__(16) __bf16 sA[128 * 32];
    __shared__ __align__(16) __bf16 sB[64 * 32];

    const int tid = threadIdx.x;
    const int bm = blockIdx.y * 128, bn = blockIdx.x * 64;
    const int lane = tid & 63;
    const int wave = tid >> 6;
    const int wm = (wave & 1) * 64;
    const int wn = (wave >> 1) * 32;
    const int l15 = lane & 15, quad = lane >> 4;

    floatx4 acc[4][2];
    #pragma unroll
    for (int mi = 0; mi < 4; ++mi)
        #pragma unroll
        for (int ni = 0; ni < 2; ++ni)
            acc[mi][ni] = (floatx4){0.f, 0.f, 0.f, 0.f};

    const int ciA0 = tid,       rA0 = ciA0 >> 2, qA0 = (ciA0 & 3) ^ (rA0 & 3);
    const int ciA1 = 256 + tid, rA1 = ciA1 >> 2, qA1 = (ciA1 & 3) ^ (rA1 & 3);
    const int rB = tid >> 2,    qB = (tid & 3) ^ (rB & 3);
    const __bf16* gA0 = Xb + (size_t)(bm + rA0) * Dm + qA0 * 8;
    const __bf16* gA1 = Xb + (size_t)(bm + rA1) * Dm + qA1 * 8;
    const __bf16* gB  = WTb + (size_t)(bn + rB) * Dm + qB * 8;
    char* lA0 = (char*)sA + (tid & 192) * 16;
    char* lA1 = (char*)sA + (256 + (tid & 192)) * 16;
    char* lB  = (char*)sB + (tid & 192) * 16;

    const __bf16* fA[4];
    const __bf16* fB[2];
    #pragma unroll
    for (int mi = 0; mi < 4; ++mi) {
        const int r = wm + mi * 16 + l15;
        fA[mi] = sA + r * 32 + ((quad ^ (r & 3)) * 8);
    }
    #pragma unroll
    for (int ni = 0; ni < 2; ++ni) {
        const int r = wn + ni * 16 + l15;
        fB[ni] = sB + r * 32 + ((quad ^ (r & 3)) * 8);
    }

    for (int kt = 0; kt < Dm; kt += 32) {
        async_ld16(lA0, gA0 + kt);
        async_ld16(lA1, gA1 + kt);
        async_ld16(lB,  gB  + kt);
        __syncthreads();

        bf16x8 af[4], bfr[2];
        #pragma unroll
        for (int mi = 0; mi < 4; ++mi) af[mi] = *(const bf16x8*)fA[mi];
        #pragma unroll
        for (int ni = 0; ni < 2; ++ni) bfr[ni] = *(const bf16x8*)fB[ni];
        #pragma unroll
        for (int mi = 0; mi < 4; ++mi)
            #pragma unroll
            for (int ni = 0; ni < 2; ++ni)
                acc[mi][ni] = __builtin_amdgcn_mfma_f32_16x16x32_bf16(
                    af[mi], bfr[ni], acc[mi][ni], 0, 0, 0);
        __syncthreads();
    }

    #pragma unroll
    for (int mi = 0; mi < 4; ++mi) {
        #pragma unroll
        for (int ni = 0; ni < 2; ++ni) {
            const int n = bn + wn + ni * 16 + l15;
            const float bv = bias[n];
            const int h = n >> 6, d = n & 63;
            #pragma unroll
            for (int reg = 0; reg < 4; ++reg) {
                const int m = bm + wm + mi * 16 + quad * 4 + reg;
                const int b = m >> 10, s = m & 1023;
                float v = acc[mi][ni][reg] + bv;
                if (do_relu) v = fmaxf(v, 0.0f);
                v *= escale;
                if (layout == 0)
                    ((__bf16*)outp)[((size_t)(b * Hn + h) * 1024 + s) * 64 + d] = (__bf16)v;
                else if (layout == 1)
                    ((__bf16*)outp)[((size_t)(b * Hn + h) * 64 + d) * 1024 + s] = (__bf16)v;
                else
                    ((float*)outp)[(size_t)m * 1024 + n] = v;
            }
        }
    }
}

// ---------------------------------------------------------------------------
// Flash attention v3: round-3-verified dataflow (S = Q·K^T, P via wave-private
// LDS, PV with verified 16x16x32 MFMA) + no-max softmax: post-ReLU Q,K give
// scores >= 0 and bounded, Q pre-scaled by log2(e)/32 so p = exp2(sc) in
// [1, ~30] — no overflow/underflow; fminf clamp for safety. No per-iter
// shuffles; row-sum is per-lane, reduced once at the end.
// Block = (b, h, 128 q rows); wave = 32 q rows. 64-key tiles, double-buffered.
// ---------------------------------------------------------------------------
__global__ __launch_bounds__(256, 2) void flash_attn_kernel(
    const __bf16* __restrict__ Qh,  // [B,H,S,HD]  (pre-scaled by log2e/32)
    const __bf16* __restrict__ Kh,  // [B,H,S,HD]
    const __bf16* __restrict__ Vt,  // [B,H,HD,S]
    __bf16* __restrict__ ctx)       // [B,S,D]
{
    __shared__ __align__(16) char sKV[2][16384];   // per buf: K 8KB | V^T 8KB
    __shared__ __align__(16) __bf16 sP[4][32 * 64];

    const int tid = threadIdx.x;
    const int wave = tid >> 6, lane = tid & 63;
    const int l15 = lane & 15, quad = lane >> 4;
    const int b = blockIdx.z, h = blockIdx.y;
    const int bh = b * Hn + h;
    const int qb = blockIdx.x * 128 + wave * 32;

    // Q fragments (A-operand), held for the whole kernel
    bf16x8 aQ[2][2];
    #pragma unroll
    for (int mi = 0; mi < 2; ++mi)
        #pragma unroll
        for (int ks = 0; ks < 2; ++ks)
            aQ[mi][ks] = *(const bf16x8*)(Qh +
                (size_t)(bh * Sn + qb + mi * 16 + l15) * 64 + ks * 32 + quad * 8);

    // staging: slots s0 = tid (rows 0..31), s1 = 256+tid (rows 32..63)
    const int s0 = tid, s1 = tid + 256;
    const int r0 = s0 >> 3, q0c = (s0 & 7) ^ (r0 & 7);
    const int r1 = s1 >> 3, q1c = (s1 & 7) ^ (r1 & 7);
    const __bf16* gK0 = Kh + (size_t)(bh * Sn + r0) * 64 + q0c * 8;
    const __bf16* gK1 = Kh + (size_t)(bh * Sn + r1) * 64 + q1c * 8;
    const __bf16* gV0 = Vt + (size_t)(bh * 64 + r0) * Sn + q0c * 8;
    const __bf16* gV1 = Vt + (size_t)(bh * 64 + r1) * Sn + q1c * 8;
    const int wofs = (tid & 192) * 16;

    floatx4 oacc[2][4];
    #pragma unroll
    for (int mi = 0; mi < 2; ++mi)
        #pragma unroll
        for (int nf = 0; nf < 4; ++nf)
            oacc[mi][nf] = (floatx4){0.f, 0.f, 0.f, 0.f};
    float lsum[2][4];
    #pragma unroll
    for (int mi = 0; mi < 2; ++mi)
        #pragma unroll
        for (int r = 0; r < 4; ++r) lsum[mi][r] = 0.0f;

    __bf16* sPw = sP[wave];

    // prefetch tile 0 into buf 0
    {
        char* bK = sKV[0];
        char* bV = sKV[0] + 8192;
        async_ld16(bK + wofs,        gK0);
        async_ld16(bK + 4096 + wofs, gK1);
        async_ld16(bV + wofs,        gV0);
        async_ld16(bV + 4096 + wofs, gV1);
    }

    int cur = 0;
    for (int it = 0; it < 16; ++it) {
        __syncthreads();   // staged loads drained (vmcnt) + all waves ready

        if (it + 1 < 16) {
            const int t0n = (it + 1) * 64;
            char* bK = sKV[cur ^ 1];
            char* bV = sKV[cur ^ 1] + 8192;
            async_ld16(bK + wofs,        gK0 + (size_t)t0n * 64);
            async_ld16(bK + 4096 + wofs, gK1 + (size_t)t0n * 64);
            async_ld16(bV + wofs,        gV0 + t0n);
            async_ld16(bV + 4096 + wofs, gV1 + t0n);
        }

        const __bf16* sK = (const __bf16*)sKV[cur];
        const __bf16* sV = (const __bf16*)(sKV[cur] + 8192);

        // ---- S = Q·K^T : sc[mi][nf], col=key(l15), row=q(quad*4+r) ----
        floatx4 sc[2][4];
        #pragma unroll
        for (int mi = 0; mi < 2; ++mi)
            #pragma unroll
            for (int nf = 0; nf < 4; ++nf)
                sc[mi][nf] = (floatx4){0.f, 0.f, 0.f, 0.f};
        #pragma unroll
        for (int ks = 0; ks < 2; ++ks) {
            bf16x8 bK[4];
            #pragma unroll
            for (int nf = 0; nf < 4; ++nf) {
                const int n = nf * 16 + l15;
                bK[nf] = *(const bf16x8*)(sK + (n * 8 + (((ks << 2) + quad) ^ (n & 7))) * 8);
            }
            #pragma unroll
            for (int mi = 0; mi < 2; ++mi)
                #pragma unroll
                for (int nf = 0; nf < 4; ++nf)
                    sc[mi][nf] = __builtin_amdgcn_mfma_f32_16x16x32_bf16(
                        aQ[mi][ks], bK[nf], sc[mi][nf], 0, 0, 0);
        }

        // ---- p = exp2(sc) (no max shift; scale pre-folded into Q) ----
        #pragma unroll
        for (int mi = 0; mi < 2; ++mi)
            #pragma unroll
            for (int nf = 0; nf < 4; ++nf) {
                const int t = nf * 16 + l15;
                #pragma unroll
                for (int r = 0; r < 4; ++r) {
                    const float p = __builtin_amdgcn_exp2f(fminf(sc[mi][nf][r], 126.0f));
                    const __bf16 pb = (__bf16)p;
                    lsum[mi][r] += (float)pb;
                    const int rr = mi * 16 + quad * 4 + r;
                    sPw[(rr * 8 + ((t >> 3) ^ (rr & 7))) * 8 + (t & 7)] = pb;
                }
            }

        // ---- PV (sP wave-private: no barrier, lgkmcnt only) ----
        #pragma unroll
        for (int ks = 0; ks < 2; ++ks) {
            bf16x8 aP[2], bV[4];
            #pragma unroll
            for (int mi = 0; mi < 2; ++mi) {
                const int r = mi * 16 + l15;
                aP[mi] = *(const bf16x8*)(sPw + (r * 8 + (((ks << 2) + quad) ^ (r & 7))) * 8);
            }
            #pragma unroll
            for (int nf = 0; nf < 4; ++nf) {
                const int n = nf * 16 + l15;
                bV[nf] = *(const bf16x8*)(sV + (n * 8 + (((ks << 2) + quad) ^ (n & 7))) * 8);
            }
            #pragma unroll
            for (int mi = 0; mi < 2; ++mi)
                #pragma unroll
                for (int nf = 0; nf < 4; ++nf)
                    oacc[mi][nf] = __builtin_amdgcn_mfma_f32_16x16x32_bf16(
                        aP[mi], bV[nf], oacc[mi][nf], 0, 0, 0);
        }

        cur ^= 1;
    }

    // ---- one-time row-sum reduction across the 16 key-lanes ----
    float linv[2][4];
    #pragma unroll
    for (int mi = 0; mi < 2; ++mi)
        #pragma unroll
        for (int r = 0; r < 4; ++r) {
            float l = lsum[mi][r];
            l += __shfl_xor(l, 1, 64);
            l += __shfl_xor(l, 2, 64);
            l += __shfl_xor(l, 4, 64);
            l += __shfl_xor(l, 8, 64);
            linv[mi][r] = 1.0f / l;
        }

    // ---- epilogue: O layout col=d(l15), row=q(quad*4+reg) ----
    #pragma unroll
    for (int mi = 0; mi < 2; ++mi)
        #pragma unroll
        for (int nf = 0; nf < 4; ++nf) {
            const int d = h * 64 + nf * 16 + l15;
            #pragma unroll
            for (int reg = 0; reg < 4; ++reg) {
                const int s = qb + mi * 16 + quad * 4 + reg;
                ctx[(size_t)(b * Sn + s) * Dm + d] =
                    (__bf16)(oacc[mi][nf][reg] * linv[mi][reg]);
            }
        }
}

// ---------------------------------------------------------------------------
extern "C" void kernel_launch(void* const* d_in, const int* in_sizes, int n_in,
                              void* d_out, int out_size, void* d_ws, size_t ws_size,
                              hipStream_t stream)
{
    const float* q  = (const float*)d_in[0];
    const float* k  = (const float*)d_in[1];
    const float* v  = (const float*)d_in[2];
    const float* Wq = (const float*)d_in[3];
    const float* bq = (const float*)d_in[4];
    const float* Wk = (const float*)d_in[5];
    const float* bk = (const float*)d_in[6];
    const float* Wv = (const float*)d_in[7];
    const float* bv = (const float*)d_in[8];
    const float* Wo = (const float*)d_in[9];
    const float* bo = (const float*)d_in[10];

    char* ws = (char*)d_ws;
    const size_t MB = 1024 * 1024;
    __bf16* qb_ = (__bf16*)(ws);            // 8 MB [4096][1024]
    __bf16* kb_ = (__bf16*)(ws + 8 * MB);
    __bf16* vb_ = (__bf16*)(ws + 16 * MB);
    __bf16* WTq = (__bf16*)(ws + 24 * MB);  // 2 MB each [N][K]
    __bf16* WTk = (__bf16*)(ws + 26 * MB);
    __bf16* WTv = (__bf16*)(ws + 28 * MB);
    __bf16* WTo = (__bf16*)(ws + 30 * MB);
    __bf16* Qh  = (__bf16*)(ws + 32 * MB);  // 8 MB [B,H,S,HD] (pre-scaled)
    __bf16* Kh  = (__bf16*)(ws + 40 * MB);  // 8 MB [B,H,S,HD]
    __bf16* Vt  = (__bf16*)(ws + 48 * MB);  // 8 MB [B,H,HD,S]
    __bf16* ctx = (__bf16*)(ws + 56 * MB);  // 8 MB [B,S,D]

    cast_qkv_kernel<<<dim3(2048, 3), 256, 0, stream>>>(q, k, v, qb_, kb_, vb_);
    cast_wt_kernel<<<dim3(16, 16, 4), 256, 0, stream>>>(Wq, Wk, Wv, Wo,
                                                        WTq, WTk, WTv, WTo);

    const float QSCALE = 0.0450842200f;  // log2(e) / 32
    const dim3 gg(16, 32), tb(256);
    gemm_bf16_kernel<<<gg, tb, 0, stream>>>(qb_, WTq, bq, Qh, 0, 1, QSCALE);
    gemm_bf16_kernel<<<gg, tb, 0, stream>>>(kb_, WTk, bk, Kh, 0, 1, 1.0f);
    gemm_bf16_kernel<<<gg, tb, 0, stream>>>(vb_, WTv, bv, Vt, 1, 1, 1.0f);

    flash_attn_kernel<<<dim3(8, Hn, 4), 256, 0, stream>>>(Qh, Kh, Vt, ctx);

    gemm_bf16_kernel<<<gg, tb, 0, stream>>>(ctx, WTo, bo, d_out, 3, 0, 1.0f);
}

// Round 6
// 229.717 us; speedup vs baseline: 3.9029x; 1.0788x over previous
//
#include <hip/hip_runtime.h>
#include <math.h>

#define Dm 1024
#define Hn 16
#define HDn 64
#define Sn 1024

typedef __attribute__((ext_vector_type(8))) __bf16 bf16x8;
typedef __attribute__((ext_vector_type(4))) float floatx4;

__device__ __forceinline__ void async_ld16(void* lds, const void* g) {
    __builtin_amdgcn_global_load_lds(
        (const __attribute__((address_space(1))) void*)g,
        (__attribute__((address_space(3))) void*)lds,
        16, 0, 0);
}

// ---------------------------------------------------------------------------
// fp32 -> bf16 cast for q,k,v (blockIdx.y selects tensor), 8 elems/thread
// ---------------------------------------------------------------------------
__global__ __launch_bounds__(256) void cast_qkv_kernel(
    const float* __restrict__ a, const float* __restrict__ b, const float* __restrict__ c,
    __bf16* __restrict__ oa, __bf16* __restrict__ ob, __bf16* __restrict__ oc)
{
    const int lin = blockIdx.x * 256 + threadIdx.x;
    const float* src = (blockIdx.y == 0) ? a : (blockIdx.y == 1) ? b : c;
    __bf16* dst = (blockIdx.y == 0) ? oa : (blockIdx.y == 1) ? ob : oc;
    const float4 v0 = ((const float4*)src)[lin * 2];
    const float4 v1 = ((const float4*)src)[lin * 2 + 1];
    bf16x8 o;
    o[0] = (__bf16)v0.x; o[1] = (__bf16)v0.y; o[2] = (__bf16)v0.z; o[3] = (__bf16)v0.w;
    o[4] = (__bf16)v1.x; o[5] = (__bf16)v1.y; o[6] = (__bf16)v1.z; o[7] = (__bf16)v1.w;
    ((bf16x8*)dst)[lin] = o;
}

// ---------------------------------------------------------------------------
// W [k][n] fp32  ->  WT [n][k] bf16
// ---------------------------------------------------------------------------
__global__ __launch_bounds__(256) void cast_wt_kernel(
    const float* __restrict__ W0, const float* __restrict__ W1,
    const float* __restrict__ W2, const float* __restrict__ W3,
    __bf16* __restrict__ O0, __bf16* __restrict__ O1,
    __bf16* __restrict__ O2, __bf16* __restrict__ O3)
{
    __shared__ float sT[64][65];
    const int z = blockIdx.z;
    const float* W = (z == 0) ? W0 : (z == 1) ? W1 : (z == 2) ? W2 : W3;
    __bf16* O = (z == 0) ? O0 : (z == 1) ? O1 : (z == 2) ? O2 : O3;

    const int tid = threadIdx.x;
    const int bi = blockIdx.y * 64, bj = blockIdx.x * 64;
    const int colr = tid & 63, rowg = tid >> 6;

    #pragma unroll
    for (int i = 0; i < 16; ++i) {
        const int kk = i * 4 + rowg;
        sT[kk][colr] = W[(size_t)(bi + kk) * Dm + bj + colr];
    }
    __syncthreads();
    #pragma unroll
    for (int i = 0; i < 16; ++i) {
        const int rn = i * 4 + rowg;
        O[(size_t)(bj + rn) * Dm + bi + colr] = (__bf16)sT[colr][rn];
    }
}

// ---------------------------------------------------------------------------
// bf16 MFMA GEMM, m97 config: 128x128 tile, BK=32, 4 waves x (64x64 = 4x4
// frags of 16x16x32), global_load_lds width-16 staging, XOR chunk swizzle.
// blockIdx.z selects one of up to 3 problem instances (fused QKV).
// layout 0: bf16 [B,H,S,HD]; 1: bf16 [B,H,HD,S]; 3: fp32 flat.
// ---------------------------------------------------------------------------
struct GemmArgs {
    const __bf16* X[3];
    const __bf16* WT[3];
    const float*  bias[3];
    void*         out[3];
    int   layout[3];
    int   relu[3];
    float esc[3];
};

__global__ __launch_bounds__(256) void gemm_bf16_kernel(GemmArgs args)
{
    __shared__ __align__(16) __bf16 sA[128 * 32];
    __shared__ __align__(16) __bf16 sB[128 * 32];

    const int z = blockIdx.z;
    const __bf16* __restrict__ Xb  = args.X[z];
    const __bf16* __restrict__ WTb = args.WT[z];
    const float*  __restrict__ bias = args.bias[z];
    void* __restrict__ outp = args.out[z];
    const int layout = args.layout[z];
    const int do_relu = args.relu[z];
    const float escale = args.esc[z];

    const int tid = threadIdx.x;
    const int bm = blockIdx.y * 128, bn = blockIdx.x * 128;
    const int lane = tid & 63;
    const int wave = tid >> 6;
    const int wm = (wave & 1) * 64;
    const int wn = (wave >> 1) * 64;
    const int l15 = lane & 15, quad = lane >> 4;

    floatx4 acc[4][4];
    #pragma unroll
    for (int mi = 0; mi < 4; ++mi)
        #pragma unroll
        for (int ni = 0; ni < 4; ++ni)
            acc[mi][ni] = (floatx4){0.f, 0.f, 0.f, 0.f};

    // staging: 512 chunks per tile for A and B; thread does chunks tid, tid+256
    const int c0 = tid,       r0 = c0 >> 2, q0 = (c0 & 3) ^ (r0 & 3);
    const int c1 = tid + 256, r1 = c1 >> 2, q1 = (c1 & 3) ^ (r1 & 3);
    const __bf16* gA0 = Xb  + (size_t)(bm + r0) * Dm + q0 * 8;
    const __bf16* gA1 = Xb  + (size_t)(bm + r1) * Dm + q1 * 8;
    const __bf16* gB0 = WTb + (size_t)(bn + r0) * Dm + q0 * 8;
    const __bf16* gB1 = WTb + (size_t)(bn + r1) * Dm + q1 * 8;
    char* lA0 = (char*)sA + (tid & 192) * 16;
    char* lA1 = (char*)sA + (256 + (tid & 192)) * 16;
    char* lB0 = (char*)sB + (tid & 192) * 16;
    char* lB1 = (char*)sB + (256 + (tid & 192)) * 16;

    // fragment LDS addresses (invariant across K loop)
    const __bf16* fA[4];
    const __bf16* fB[4];
    #pragma unroll
    for (int mi = 0; mi < 4; ++mi) {
        const int r = wm + mi * 16 + l15;
        fA[mi] = sA + r * 32 + ((quad ^ (r & 3)) * 8);
    }
    #pragma unroll
    for (int ni = 0; ni < 4; ++ni) {
        const int r = wn + ni * 16 + l15;
        fB[ni] = sB + r * 32 + ((quad ^ (r & 3)) * 8);
    }

    for (int kt = 0; kt < Dm; kt += 32) {
        async_ld16(lA0, gA0 + kt);
        async_ld16(lA1, gA1 + kt);
        async_ld16(lB0, gB0 + kt);
        async_ld16(lB1, gB1 + kt);
        __syncthreads();

        bf16x8 af[4], bfr[4];
        #pragma unroll
        for (int mi = 0; mi < 4; ++mi) af[mi] = *(const bf16x8*)fA[mi];
        #pragma unroll
        for (int ni = 0; ni < 4; ++ni) bfr[ni] = *(const bf16x8*)fB[ni];
        #pragma unroll
        for (int mi = 0; mi < 4; ++mi)
            #pragma unroll
            for (int ni = 0; ni < 4; ++ni)
                acc[mi][ni] = __builtin_amdgcn_mfma_f32_16x16x32_bf16(
                    af[mi], bfr[ni], acc[mi][ni], 0, 0, 0);
        __syncthreads();
    }

    // epilogue: C/D layout col=lane&15, row=quad*4+reg
    #pragma unroll
    for (int mi = 0; mi < 4; ++mi) {
        #pragma unroll
        for (int ni = 0; ni < 4; ++ni) {
            const int n = bn + wn + ni * 16 + l15;
            const float bv = bias[n];
            const int h = n >> 6, d = n & 63;
            #pragma unroll
            for (int reg = 0; reg < 4; ++reg) {
                const int m = bm + wm + mi * 16 + quad * 4 + reg;
                const int b = m >> 10, s = m & 1023;
                float v = acc[mi][ni][reg] + bv;
                if (do_relu) v = fmaxf(v, 0.0f);
                v *= escale;
                if (layout == 0)
                    ((__bf16*)outp)[((size_t)(b * Hn + h) * 1024 + s) * 64 + d] = (__bf16)v;
                else if (layout == 1)
                    ((__bf16*)outp)[((size_t)(b * Hn + h) * 64 + d) * 1024 + s] = (__bf16)v;
                else
                    ((float*)outp)[(size_t)m * 1024 + n] = v;
            }
        }
    }
}

// ---------------------------------------------------------------------------
// Flash attention v3 (round-5-verified): S = Q·K^T, no-max softmax (post-ReLU
// Q,K => scores in [0, ~4.5] log2-domain; Q pre-scaled by log2(e)/32), P via
// wave-private LDS, PV with 16x16x32 MFMA. 64-key tiles, double-buffered.
// ---------------------------------------------------------------------------
__global__ __launch_bounds__(256, 2) void flash_attn_kernel(
    const __bf16* __restrict__ Qh,  // [B,H,S,HD]  (pre-scaled by log2e/32)
    const __bf16* __restrict__ Kh,  // [B,H,S,HD]
    const __bf16* __restrict__ Vt,  // [B,H,HD,S]
    __bf16* __restrict__ ctx)       // [B,S,D]
{
    __shared__ __align__(16) char sKV[2][16384];   // per buf: K 8KB | V^T 8KB
    __shared__ __align__(16) __bf16 sP[4][32 * 64];

    const int tid = threadIdx.x;
    const int wave = tid >> 6, lane = tid & 63;
    const int l15 = lane & 15, quad = lane >> 4;
    const int b = blockIdx.z, h = blockIdx.y;
    const int bh = b * Hn + h;
    const int qb = blockIdx.x * 128 + wave * 32;

    bf16x8 aQ[2][2];
    #pragma unroll
    for (int mi = 0; mi < 2; ++mi)
        #pragma unroll
        for (int ks = 0; ks < 2; ++ks)
            aQ[mi][ks] = *(const bf16x8*)(Qh +
                (size_t)(bh * Sn + qb + mi * 16 + l15) * 64 + ks * 32 + quad * 8);

    const int s0 = tid, s1 = tid + 256;
    const int r0 = s0 >> 3, q0c = (s0 & 7) ^ (r0 & 7);
    const int r1 = s1 >> 3, q1c = (s1 & 7) ^ (r1 & 7);
    const __bf16* gK0 = Kh + (size_t)(bh * Sn + r0) * 64 + q0c * 8;
    const __bf16* gK1 = Kh + (size_t)(bh * Sn + r1) * 64 + q1c * 8;
    const __bf16* gV0 = Vt + (size_t)(bh * 64 + r0) * Sn + q0c * 8;
    const __bf16* gV1 = Vt + (size_t)(bh * 64 + r1) * Sn + q1c * 8;
    const int wofs = (tid & 192) * 16;

    floatx4 oacc[2][4];
    #pragma unroll
    for (int mi = 0; mi < 2; ++mi)
        #pragma unroll
        for (int nf = 0; nf < 4; ++nf)
            oacc[mi][nf] = (floatx4){0.f, 0.f, 0.f, 0.f};
    float lsum[2][4];
    #pragma unroll
    for (int mi = 0; mi < 2; ++mi)
        #pragma unroll
        for (int r = 0; r < 4; ++r) lsum[mi][r] = 0.0f;

    __bf16* sPw = sP[wave];

    {
        char* bK = sKV[0];
        char* bV = sKV[0] + 8192;
        async_ld16(bK + wofs,        gK0);
        async_ld16(bK + 4096 + wofs, gK1);
        async_ld16(bV + wofs,        gV0);
        async_ld16(bV + 4096 + wofs, gV1);
    }

    int cur = 0;
    for (int it = 0; it < 16; ++it) {
        __syncthreads();

        if (it + 1 < 16) {
            const int t0n = (it + 1) * 64;
            char* bK = sKV[cur ^ 1];
            char* bV = sKV[cur ^ 1] + 8192;
            async_ld16(bK + wofs,        gK0 + (size_t)t0n * 64);
            async_ld16(bK + 4096 + wofs, gK1 + (size_t)t0n * 64);
            async_ld16(bV + wofs,        gV0 + t0n);
            async_ld16(bV + 4096 + wofs, gV1 + t0n);
        }

        const __bf16* sK = (const __bf16*)sKV[cur];
        const __bf16* sV = (const __bf16*)(sKV[cur] + 8192);

        floatx4 sc[2][4];
        #pragma unroll
        for (int mi = 0; mi < 2; ++mi)
            #pragma unroll
            for (int nf = 0; nf < 4; ++nf)
                sc[mi][nf] = (floatx4){0.f, 0.f, 0.f, 0.f};
        #pragma unroll
        for (int ks = 0; ks < 2; ++ks) {
            bf16x8 bK[4];
            #pragma unroll
            for (int nf = 0; nf < 4; ++nf) {
                const int n = nf * 16 + l15;
                bK[nf] = *(const bf16x8*)(sK + (n * 8 + (((ks << 2) + quad) ^ (n & 7))) * 8);
            }
            #pragma unroll
            for (int mi = 0; mi < 2; ++mi)
                #pragma unroll
                for (int nf = 0; nf < 4; ++nf)
                    sc[mi][nf] = __builtin_amdgcn_mfma_f32_16x16x32_bf16(
                        aQ[mi][ks], bK[nf], sc[mi][nf], 0, 0, 0);
        }

        #pragma unroll
        for (int mi = 0; mi < 2; ++mi)
            #pragma unroll
            for (int nf = 0; nf < 4; ++nf) {
                const int t = nf * 16 + l15;
                #pragma unroll
                for (int r = 0; r < 4; ++r) {
                    const float p = __builtin_amdgcn_exp2f(fminf(sc[mi][nf][r], 126.0f));
                    const __bf16 pb = (__bf16)p;
                    lsum[mi][r] += (float)pb;
                    const int rr = mi * 16 + quad * 4 + r;
                    sPw[(rr * 8 + ((t >> 3) ^ (rr & 7))) * 8 + (t & 7)] = pb;
                }
            }

        #pragma unroll
        for (int ks = 0; ks < 2; ++ks) {
            bf16x8 aP[2], bV[4];
            #pragma unroll
            for (int mi = 0; mi < 2; ++mi) {
                const int r = mi * 16 + l15;
                aP[mi] = *(const bf16x8*)(sPw + (r * 8 + (((ks << 2) + quad) ^ (r & 7))) * 8);
            }
            #pragma unroll
            for (int nf = 0; nf < 4; ++nf) {
                const int n = nf * 16 + l15;
                bV[nf] = *(const bf16x8*)(sV + (n * 8 + (((ks << 2) + quad) ^ (n & 7))) * 8);
            }
            #pragma unroll
            for (int mi = 0; mi < 2; ++mi)
                #pragma unroll
                for (int nf = 0; nf < 4; ++nf)
                    oacc[mi][nf] = __builtin_amdgcn_mfma_f32_16x16x32_bf16(
                        aP[mi], bV[nf], oacc[mi][nf], 0, 0, 0);
        }

        cur ^= 1;
    }

    float linv[2][4];
    #pragma unroll
    for (int mi = 0; mi < 2; ++mi)
        #pragma unroll
        for (int r = 0; r < 4; ++r) {
            float l = lsum[mi][r];
            l += __shfl_xor(l, 1, 64);
            l += __shfl_xor(l, 2, 64);
            l += __shfl_xor(l, 4, 64);
            l += __shfl_xor(l, 8, 64);
            linv[mi][r] = 1.0f / l;
        }

    #pragma unroll
    for (int mi = 0; mi < 2; ++mi)
        #pragma unroll
        for (int nf = 0; nf < 4; ++nf) {
            const int d = h * 64 + nf * 16 + l15;
            #pragma unroll
            for (int reg = 0; reg < 4; ++reg) {
                const int s = qb + mi * 16 + quad * 4 + reg;
                ctx[(size_t)(b * Sn + s) * Dm + d] =
                    (__bf16)(oacc[mi][nf][reg] * linv[mi][reg]);
            }
        }
}

// ---------------------------------------------------------------------------
extern "C" void kernel_launch(void* const* d_in, const int* in_sizes, int n_in,
                              void* d_out, int out_size, void* d_ws, size_t ws_size,
                              hipStream_t stream)
{
    const float* q  = (const float*)d_in[0];
    const float* k  = (const float*)d_in[1];
    const float* v  = (const float*)d_in[2];
    const float* Wq = (const float*)d_in[3];
    const float* bq = (const float*)d_in[4];
    const float* Wk = (const float*)d_in[5];
    const float* bk = (const float*)d_in[6];
    const float* Wv = (const float*)d_in[7];
    const float* bv = (const float*)d_in[8];
    const float* Wo = (const float*)d_in[9];
    const float* bo = (const float*)d_in[10];

    char* ws = (char*)d_ws;
    const size_t MB = 1024 * 1024;
    __bf16* qb_ = (__bf16*)(ws);            // 8 MB [4096][1024]
    __bf16* kb_ = (__bf16*)(ws + 8 * MB);
    __bf16* vb_ = (__bf16*)(ws + 16 * MB);
    __bf16* WTq = (__bf16*)(ws + 24 * MB);  // 2 MB each [N][K]
    __bf16* WTk = (__bf16*)(ws + 26 * MB);
    __bf16* WTv = (__bf16*)(ws + 28 * MB);
    __bf16* WTo = (__bf16*)(ws + 30 * MB);
    __bf16* Qh  = (__bf16*)(ws + 32 * MB);  // 8 MB [B,H,S,HD] (pre-scaled)
    __bf16* Kh  = (__bf16*)(ws + 40 * MB);  // 8 MB [B,H,S,HD]
    __bf16* Vt  = (__bf16*)(ws + 48 * MB);  // 8 MB [B,H,HD,S]
    __bf16* ctx = (__bf16*)(ws + 56 * MB);  // 8 MB [B,S,D]

    cast_qkv_kernel<<<dim3(2048, 3), 256, 0, stream>>>(q, k, v, qb_, kb_, vb_);
    cast_wt_kernel<<<dim3(16, 16, 4), 256, 0, stream>>>(Wq, Wk, Wv, Wo,
                                                        WTq, WTk, WTv, WTo);

    const float QSCALE = 0.0450842200f;  // log2(e) / 32

    GemmArgs qkv;
    qkv.X[0] = qb_;  qkv.X[1] = kb_;  qkv.X[2] = vb_;
    qkv.WT[0] = WTq; qkv.WT[1] = WTk; qkv.WT[2] = WTv;
    qkv.bias[0] = bq; qkv.bias[1] = bk; qkv.bias[2] = bv;
    qkv.out[0] = Qh;  qkv.out[1] = Kh;  qkv.out[2] = Vt;
    qkv.layout[0] = 0; qkv.layout[1] = 0; qkv.layout[2] = 1;
    qkv.relu[0] = 1;   qkv.relu[1] = 1;   qkv.relu[2] = 1;
    qkv.esc[0] = QSCALE; qkv.esc[1] = 1.0f; qkv.esc[2] = 1.0f;
    gemm_bf16_kernel<<<dim3(8, 32, 3), 256, 0, stream>>>(qkv);

    flash_attn_kernel<<<dim3(8, Hn, 4), 256, 0, stream>>>(Qh, Kh, Vt, ctx);

    GemmArgs og;
    og.X[0] = ctx;  og.X[1] = ctx;  og.X[2] = ctx;
    og.WT[0] = WTo; og.WT[1] = WTo; og.WT[2] = WTo;
    og.bias[0] = bo; og.bias[1] = bo; og.bias[2] = bo;
    og.out[0] = d_out; og.out[1] = d_out; og.out[2] = d_out;
    og.layout[0] = 3; og.layout[1] = 3; og.layout[2] = 3;
    og.relu[0] = 0;   og.relu[1] = 0;   og.relu[2] = 0;
    og.esc[0] = 1.0f; og.esc[1] = 1.0f; og.esc[2] = 1.0f;
    gemm_bf16_kernel<<<dim3(8, 32, 1), 256, 0, stream>>>(og);
}

// Round 7
// 228.133 us; speedup vs baseline: 3.9300x; 1.0069x over previous
//
#include <hip/hip_runtime.h>
#include <math.h>

#define Dm 1024
#define Hn 16
#define HDn 64
#define Sn 1024

typedef __attribute__((ext_vector_type(8))) __bf16 bf16x8;
typedef __attribute__((ext_vector_type(4))) float floatx4;

__device__ __forceinline__ void async_ld16(void* lds, const void* g) {
    __builtin_amdgcn_global_load_lds(
        (const __attribute__((address_space(1))) void*)g,
        (__attribute__((address_space(3))) void*)lds,
        16, 0, 0);
}

// ---------------------------------------------------------------------------
// Prep kernel. grid (2048, 1, 8), 256 thr.
//  z 0..2 : fp32->bf16 cast of q/k/v (x < 2048, 8 elems/thread)
//  z 3..6 : W [k][n] fp32 -> WT [n][k] bf16, 64x64 tiles (x < 256)
//  z 7    : zero d_out (x < 2048, 2 float4/thread)
// ---------------------------------------------------------------------------
struct PrepArgs {
    const float* qkv[3];
    __bf16*      qkv_o[3];
    const float* W[4];
    __bf16*      WT[4];
    float*       out_zero;
};

__global__ __launch_bounds__(256) void prep_kernel(PrepArgs a)
{
    __shared__ float sT[64][65];
    const int z = blockIdx.z, x = blockIdx.x, tid = threadIdx.x;

    if (z < 3) {
        const float* src = a.qkv[z];
        __bf16* dst = a.qkv_o[z];
        const int lin = x * 256 + tid;
        const float4 v0 = ((const float4*)src)[lin * 2];
        const float4 v1 = ((const float4*)src)[lin * 2 + 1];
        bf16x8 o;
        o[0] = (__bf16)v0.x; o[1] = (__bf16)v0.y; o[2] = (__bf16)v0.z; o[3] = (__bf16)v0.w;
        o[4] = (__bf16)v1.x; o[5] = (__bf16)v1.y; o[6] = (__bf16)v1.z; o[7] = (__bf16)v1.w;
        ((bf16x8*)dst)[lin] = o;
    } else if (z < 7) {
        if (x >= 256) return;
        const float* W = a.W[z - 3];
        __bf16* O = a.WT[z - 3];
        const int bi = (x >> 4) * 64, bj = (x & 15) * 64;
        const int colr = tid & 63, rowg = tid >> 6;
        #pragma unroll
        for (int i = 0; i < 16; ++i) {
            const int kk = i * 4 + rowg;
            sT[kk][colr] = W[(size_t)(bi + kk) * Dm + bj + colr];
        }
        __syncthreads();
        #pragma unroll
        for (int i = 0; i < 16; ++i) {
            const int rn = i * 4 + rowg;
            O[(size_t)(bj + rn) * Dm + bi + colr] = (__bf16)sT[colr][rn];
        }
    } else {
        float4* o = (float4*)a.out_zero;
        const int i = (x * 256 + tid) * 2;
        const float4 zz = make_float4(0.f, 0.f, 0.f, 0.f);
        o[i] = zz;
        o[i + 1] = zz;
    }
}

// ---------------------------------------------------------------------------
// bf16 MFMA GEMM, m97 config: 128x128 tile, BK=32, 4 waves x (64x64 = 4x4
// frags of 16x16x32), global_load_lds width-16 staging, XOR chunk swizzle.
// XCD-aware block swizzle: XCD c owns m-tiles {4c..4c+3} x all 8 n-tiles
// (A 1MB + B 2MB fits 4MB per-XCD L2). blockIdx.z = problem instance.
// layout 0: bf16 [B,H,S,HD]; 1: bf16 [B,H,HD,S].
// ---------------------------------------------------------------------------
struct GemmArgs {
    const __bf16* X[3];
    const __bf16* WT[3];
    const float*  bias[3];
    void*         out[3];
    int   layout[3];
    float esc[3];
};

__global__ __launch_bounds__(256) void gemm_bf16_kernel(GemmArgs args)
{
    __shared__ __align__(16) __bf16 sA[128 * 32];
    __shared__ __align__(16) __bf16 sB[128 * 32];

    const int z = blockIdx.z;
    const __bf16* __restrict__ Xb  = args.X[z];
    const __bf16* __restrict__ WTb = args.WT[z];
    const float*  __restrict__ bias = args.bias[z];
    void* __restrict__ outp = args.out[z];
    const int layout = args.layout[z];
    const float escale = args.esc[z];

    const int tid = threadIdx.x;
    // XCD swizzle: id in [0,256); xcd = id&7 -> m group, (id>>3)&7 -> n
    const int id = blockIdx.x + (blockIdx.y << 3);
    const int bm = (((id & 7) << 2) | (id >> 6)) * 128;
    const int bn = ((id >> 3) & 7) * 128;

    const int lane = tid & 63;
    const int wave = tid >> 6;
    const int wm = (wave & 1) * 64;
    const int wn = (wave >> 1) * 64;
    const int l15 = lane & 15, quad = lane >> 4;

    floatx4 acc[4][4];
    #pragma unroll
    for (int mi = 0; mi < 4; ++mi)
        #pragma unroll
        for (int ni = 0; ni < 4; ++ni)
            acc[mi][ni] = (floatx4){0.f, 0.f, 0.f, 0.f};

    const int c0 = tid,       r0 = c0 >> 2, q0 = (c0 & 3) ^ (r0 & 3);
    const int c1 = tid + 256, r1 = c1 >> 2, q1 = (c1 & 3) ^ (r1 & 3);
    const __bf16* gA0 = Xb  + (size_t)(bm + r0) * Dm + q0 * 8;
    const __bf16* gA1 = Xb  + (size_t)(bm + r1) * Dm + q1 * 8;
    const __bf16* gB0 = WTb + (size_t)(bn + r0) * Dm + q0 * 8;
    const __bf16* gB1 = WTb + (size_t)(bn + r1) * Dm + q1 * 8;
    char* lA0 = (char*)sA + (tid & 192) * 16;
    char* lA1 = (char*)sA + (256 + (tid & 192)) * 16;
    char* lB0 = (char*)sB + (tid & 192) * 16;
    char* lB1 = (char*)sB + (256 + (tid & 192)) * 16;

    const __bf16* fA[4];
    const __bf16* fB[4];
    #pragma unroll
    for (int mi = 0; mi < 4; ++mi) {
        const int r = wm + mi * 16 + l15;
        fA[mi] = sA + r * 32 + ((quad ^ (r & 3)) * 8);
    }
    #pragma unroll
    for (int ni = 0; ni < 4; ++ni) {
        const int r = wn + ni * 16 + l15;
        fB[ni] = sB + r * 32 + ((quad ^ (r & 3)) * 8);
    }

    for (int kt = 0; kt < Dm; kt += 32) {
        async_ld16(lA0, gA0 + kt);
        async_ld16(lA1, gA1 + kt);
        async_ld16(lB0, gB0 + kt);
        async_ld16(lB1, gB1 + kt);
        __syncthreads();

        bf16x8 af[4], bfr[4];
        #pragma unroll
        for (int mi = 0; mi < 4; ++mi) af[mi] = *(const bf16x8*)fA[mi];
        #pragma unroll
        for (int ni = 0; ni < 4; ++ni) bfr[ni] = *(const bf16x8*)fB[ni];
        #pragma unroll
        for (int mi = 0; mi < 4; ++mi)
            #pragma unroll
            for (int ni = 0; ni < 4; ++ni)
                acc[mi][ni] = __builtin_amdgcn_mfma_f32_16x16x32_bf16(
                    af[mi], bfr[ni], acc[mi][ni], 0, 0, 0);
        __syncthreads();
    }

    #pragma unroll
    for (int mi = 0; mi < 4; ++mi) {
        #pragma unroll
        for (int ni = 0; ni < 4; ++ni) {
            const int n = bn + wn + ni * 16 + l15;
            const float bv = bias[n];
            const int h = n >> 6, d = n & 63;
            #pragma unroll
            for (int reg = 0; reg < 4; ++reg) {
                const int m = bm + wm + mi * 16 + quad * 4 + reg;
                const int b = m >> 10, s = m & 1023;
                float v = fmaxf(acc[mi][ni][reg] + bv, 0.0f) * escale;
                if (layout == 0)
                    ((__bf16*)outp)[((size_t)(b * Hn + h) * 1024 + s) * 64 + d] = (__bf16)v;
                else
                    ((__bf16*)outp)[((size_t)(b * Hn + h) * 64 + d) * 1024 + s] = (__bf16)v;
            }
        }
    }
}

// ---------------------------------------------------------------------------
// Output GEMM, split-K=2: z = K-half, 512 blocks (2/CU). Epilogue does
// fp32 atomicAdd into pre-zeroed d_out (2 commutative adds -> deterministic).
// bias added by the z==0 half only. Same XCD swizzle as above.
// ---------------------------------------------------------------------------
__global__ __launch_bounds__(256) void gemm_splitk_kernel(
    const __bf16* __restrict__ Xb, const __bf16* __restrict__ WTb,
    const float* __restrict__ bias, float* __restrict__ outp)
{
    __shared__ __align__(16) __bf16 sA[128 * 32];
    __shared__ __align__(16) __bf16 sB[128 * 32];

    const int tid = threadIdx.x;
    const int kz = blockIdx.z;           // 0 or 1: K-half
    const int id = blockIdx.x + (blockIdx.y << 3);
    const int bm = (((id & 7) << 2) | (id >> 6)) * 128;
    const int bn = ((id >> 3) & 7) * 128;

    const int lane = tid & 63;
    const int wave = tid >> 6;
    const int wm = (wave & 1) * 64;
    const int wn = (wave >> 1) * 64;
    const int l15 = lane & 15, quad = lane >> 4;

    floatx4 acc[4][4];
    #pragma unroll
    for (int mi = 0; mi < 4; ++mi)
        #pragma unroll
        for (int ni = 0; ni < 4; ++ni)
            acc[mi][ni] = (floatx4){0.f, 0.f, 0.f, 0.f};

    const int c0 = tid,       r0 = c0 >> 2, q0 = (c0 & 3) ^ (r0 & 3);
    const int c1 = tid + 256, r1 = c1 >> 2, q1 = (c1 & 3) ^ (r1 & 3);
    const int kofs = kz * 512;
    const __bf16* gA0 = Xb  + (size_t)(bm + r0) * Dm + kofs + q0 * 8;
    const __bf16* gA1 = Xb  + (size_t)(bm + r1) * Dm + kofs + q1 * 8;
    const __bf16* gB0 = WTb + (size_t)(bn + r0) * Dm + kofs + q0 * 8;
    const __bf16* gB1 = WTb + (size_t)(bn + r1) * Dm + kofs + q1 * 8;
    char* lA0 = (char*)sA + (tid & 192) * 16;
    char* lA1 = (char*)sA + (256 + (tid & 192)) * 16;
    char* lB0 = (char*)sB + (tid & 192) * 16;
    char* lB1 = (char*)sB + (256 + (tid & 192)) * 16;

    const __bf16* fA[4];
    const __bf16* fB[4];
    #pragma unroll
    for (int mi = 0; mi < 4; ++mi) {
        const int r = wm + mi * 16 + l15;
        fA[mi] = sA + r * 32 + ((quad ^ (r & 3)) * 8);
    }
    #pragma unroll
    for (int ni = 0; ni < 4; ++ni) {
        const int r = wn + ni * 16 + l15;
        fB[ni] = sB + r * 32 + ((quad ^ (r & 3)) * 8);
    }

    for (int kt = 0; kt < 512; kt += 32) {
        async_ld16(lA0, gA0 + kt);
        async_ld16(lA1, gA1 + kt);
        async_ld16(lB0, gB0 + kt);
        async_ld16(lB1, gB1 + kt);
        __syncthreads();

        bf16x8 af[4], bfr[4];
        #pragma unroll
        for (int mi = 0; mi < 4; ++mi) af[mi] = *(const bf16x8*)fA[mi];
        #pragma unroll
        for (int ni = 0; ni < 4; ++ni) bfr[ni] = *(const bf16x8*)fB[ni];
        #pragma unroll
        for (int mi = 0; mi < 4; ++mi)
            #pragma unroll
            for (int ni = 0; ni < 4; ++ni)
                acc[mi][ni] = __builtin_amdgcn_mfma_f32_16x16x32_bf16(
                    af[mi], bfr[ni], acc[mi][ni], 0, 0, 0);
        __syncthreads();
    }

    #pragma unroll
    for (int mi = 0; mi < 4; ++mi) {
        #pragma unroll
        for (int ni = 0; ni < 4; ++ni) {
            const int n = bn + wn + ni * 16 + l15;
            const float bv = (kz == 0) ? bias[n] : 0.0f;
            #pragma unroll
            for (int reg = 0; reg < 4; ++reg) {
                const int m = bm + wm + mi * 16 + quad * 4 + reg;
                atomicAdd(outp + (size_t)m * 1024 + n, acc[mi][ni][reg] + bv);
            }
        }
    }
}

// ---------------------------------------------------------------------------
// Flash attention (round-5-verified dataflow): S = Q·K^T, no-max softmax
// (post-ReLU Q,K => scores >= 0, bounded; Q pre-scaled by log2(e)/32), P via
// wave-private LDS, PV with 16x16x32 MFMA. 64-key tiles, double-buffered.
// XCD swizzle: XCD c owns 8 (b,h) pairs -> 2MB K/V resident in L2, 8x reuse.
// ---------------------------------------------------------------------------
__global__ __launch_bounds__(256, 2) void flash_attn_kernel(
    const __bf16* __restrict__ Qh,  // [B,H,S,HD]  (pre-scaled by log2e/32)
    const __bf16* __restrict__ Kh,  // [B,H,S,HD]
    const __bf16* __restrict__ Vt,  // [B,H,HD,S]
    __bf16* __restrict__ ctx)       // [B,S,D]
{
    __shared__ __align__(16) char sKV[2][16384];   // per buf: K 8KB | V^T 8KB
    __shared__ __align__(16) __bf16 sP[4][32 * 64];

    const int tid = threadIdx.x;
    const int wave = tid >> 6, lane = tid & 63;
    const int l15 = lane & 15, quad = lane >> 4;

    // XCD swizzle over 512 blocks
    const int id = blockIdx.x + (blockIdx.y << 3) + (blockIdx.z << 7);
    const int kk = id >> 3;
    const int bh = ((id & 7) << 3) | (kk & 7);
    const int b = bh >> 4, h = bh & 15;
    const int qb = (kk >> 3) * 128 + wave * 32;

    bf16x8 aQ[2][2];
    #pragma unroll
    for (int mi = 0; mi < 2; ++mi)
        #pragma unroll
        for (int ks = 0; ks < 2; ++ks)
            aQ[mi][ks] = *(const bf16x8*)(Qh +
                (size_t)(bh * Sn + qb + mi * 16 + l15) * 64 + ks * 32 + quad * 8);

    const int s0 = tid, s1 = tid + 256;
    const int r0 = s0 >> 3, q0c = (s0 & 7) ^ (r0 & 7);
    const int r1 = s1 >> 3, q1c = (s1 & 7) ^ (r1 & 7);
    const __bf16* gK0 = Kh + (size_t)(bh * Sn + r0) * 64 + q0c * 8;
    const __bf16* gK1 = Kh + (size_t)(bh * Sn + r1) * 64 + q1c * 8;
    const __bf16* gV0 = Vt + (size_t)(bh * 64 + r0) * Sn + q0c * 8;
    const __bf16* gV1 = Vt + (size_t)(bh * 64 + r1) * Sn + q1c * 8;
    const int wofs = (tid & 192) * 16;

    floatx4 oacc[2][4];
    #pragma unroll
    for (int mi = 0; mi < 2; ++mi)
        #pragma unroll
        for (int nf = 0; nf < 4; ++nf)
            oacc[mi][nf] = (floatx4){0.f, 0.f, 0.f, 0.f};
    float lsum[2][4];
    #pragma unroll
    for (int mi = 0; mi < 2; ++mi)
        #pragma unroll
        for (int r = 0; r < 4; ++r) lsum[mi][r] = 0.0f;

    __bf16* sPw = sP[wave];

    {
        char* bK = sKV[0];
        char* bV = sKV[0] + 8192;
        async_ld16(bK + wofs,        gK0);
        async_ld16(bK + 4096 + wofs, gK1);
        async_ld16(bV + wofs,        gV0);
        async_ld16(bV + 4096 + wofs, gV1);
    }

    int cur = 0;
    for (int it = 0; it < 16; ++it) {
        __syncthreads();

        if (it + 1 < 16) {
            const int t0n = (it + 1) * 64;
            char* bK = sKV[cur ^ 1];
            char* bV = sKV[cur ^ 1] + 8192;
            async_ld16(bK + wofs,        gK0 + (size_t)t0n * 64);
            async_ld16(bK + 4096 + wofs, gK1 + (size_t)t0n * 64);
            async_ld16(bV + wofs,        gV0 + t0n);
            async_ld16(bV + 4096 + wofs, gV1 + t0n);
        }

        const __bf16* sK = (const __bf16*)sKV[cur];
        const __bf16* sV = (const __bf16*)(sKV[cur] + 8192);

        floatx4 sc[2][4];
        #pragma unroll
        for (int mi = 0; mi < 2; ++mi)
            #pragma unroll
            for (int nf = 0; nf < 4; ++nf)
                sc[mi][nf] = (floatx4){0.f, 0.f, 0.f, 0.f};
        #pragma unroll
        for (int ks = 0; ks < 2; ++ks) {
            bf16x8 bK[4];
            #pragma unroll
            for (int nf = 0; nf < 4; ++nf) {
                const int n = nf * 16 + l15;
                bK[nf] = *(const bf16x8*)(sK + (n * 8 + (((ks << 2) + quad) ^ (n & 7))) * 8);
            }
            #pragma unroll
            for (int mi = 0; mi < 2; ++mi)
                #pragma unroll
                for (int nf = 0; nf < 4; ++nf)
                    sc[mi][nf] = __builtin_amdgcn_mfma_f32_16x16x32_bf16(
                        aQ[mi][ks], bK[nf], sc[mi][nf], 0, 0, 0);
        }

        #pragma unroll
        for (int mi = 0; mi < 2; ++mi)
            #pragma unroll
            for (int nf = 0; nf < 4; ++nf) {
                const int t = nf * 16 + l15;
                #pragma unroll
                for (int r = 0; r < 4; ++r) {
                    const float p = __builtin_amdgcn_exp2f(fminf(sc[mi][nf][r], 126.0f));
                    const __bf16 pb = (__bf16)p;
                    lsum[mi][r] += (float)pb;
                    const int rr = mi * 16 + quad * 4 + r;
                    sPw[(rr * 8 + ((t >> 3) ^ (rr & 7))) * 8 + (t & 7)] = pb;
                }
            }

        #pragma unroll
        for (int ks = 0; ks < 2; ++ks) {
            bf16x8 aP[2], bV[4];
            #pragma unroll
            for (int mi = 0; mi < 2; ++mi) {
                const int r = mi * 16 + l15;
                aP[mi] = *(const bf16x8*)(sPw + (r * 8 + (((ks << 2) + quad) ^ (r & 7))) * 8);
            }
            #pragma unroll
            for (int nf = 0; nf < 4; ++nf) {
                const int n = nf * 16 + l15;
                bV[nf] = *(const bf16x8*)(sV + (n * 8 + (((ks << 2) + quad) ^ (n & 7))) * 8);
            }
            #pragma unroll
            for (int mi = 0; mi < 2; ++mi)
                #pragma unroll
                for (int nf = 0; nf < 4; ++nf)
                    oacc[mi][nf] = __builtin_amdgcn_mfma_f32_16x16x32_bf16(
                        aP[mi], bV[nf], oacc[mi][nf], 0, 0, 0);
        }

        cur ^= 1;
    }

    float linv[2][4];
    #pragma unroll
    for (int mi = 0; mi < 2; ++mi)
        #pragma unroll
        for (int r = 0; r < 4; ++r) {
            float l = lsum[mi][r];
            l += __shfl_xor(l, 1, 64);
            l += __shfl_xor(l, 2, 64);
            l += __shfl_xor(l, 4, 64);
            l += __shfl_xor(l, 8, 64);
            linv[mi][r] = 1.0f / l;
        }

    #pragma unroll
    for (int mi = 0; mi < 2; ++mi)
        #pragma unroll
        for (int nf = 0; nf < 4; ++nf) {
            const int d = h * 64 + nf * 16 + l15;
            #pragma unroll
            for (int reg = 0; reg < 4; ++reg) {
                const int s = qb + mi * 16 + quad * 4 + reg;
                ctx[(size_t)(b * Sn + s) * Dm + d] =
                    (__bf16)(oacc[mi][nf][reg] * linv[mi][reg]);
            }
        }
}

// ---------------------------------------------------------------------------
extern "C" void kernel_launch(void* const* d_in, const int* in_sizes, int n_in,
                              void* d_out, int out_size, void* d_ws, size_t ws_size,
                              hipStream_t stream)
{
    const float* q  = (const float*)d_in[0];
    const float* k  = (const float*)d_in[1];
    const float* v  = (const float*)d_in[2];
    const float* Wq = (const float*)d_in[3];
    const float* bq = (const float*)d_in[4];
    const float* Wk = (const float*)d_in[5];
    const float* bk = (const float*)d_in[6];
    const float* Wv = (const float*)d_in[7];
    const float* bv = (const float*)d_in[8];
    const float* Wo = (const float*)d_in[9];
    const float* bo = (const float*)d_in[10];

    char* ws = (char*)d_ws;
    const size_t MB = 1024 * 1024;
    __bf16* qb_ = (__bf16*)(ws);            // 8 MB [4096][1024]
    __bf16* kb_ = (__bf16*)(ws + 8 * MB);
    __bf16* vb_ = (__bf16*)(ws + 16 * MB);
    __bf16* WTq = (__bf16*)(ws + 24 * MB);  // 2 MB each [N][K]
    __bf16* WTk = (__bf16*)(ws + 26 * MB);
    __bf16* WTv = (__bf16*)(ws + 28 * MB);
    __bf16* WTo = (__bf16*)(ws + 30 * MB);
    __bf16* Qh  = (__bf16*)(ws + 32 * MB);  // 8 MB [B,H,S,HD] (pre-scaled)
    __bf16* Kh  = (__bf16*)(ws + 40 * MB);  // 8 MB [B,H,S,HD]
    __bf16* Vt  = (__bf16*)(ws + 48 * MB);  // 8 MB [B,H,HD,S]
    __bf16* ctx = (__bf16*)(ws + 56 * MB);  // 8 MB [B,S,D]

    PrepArgs pa;
    pa.qkv[0] = q; pa.qkv[1] = k; pa.qkv[2] = v;
    pa.qkv_o[0] = qb_; pa.qkv_o[1] = kb_; pa.qkv_o[2] = vb_;
    pa.W[0] = Wq; pa.W[1] = Wk; pa.W[2] = Wv; pa.W[3] = Wo;
    pa.WT[0] = WTq; pa.WT[1] = WTk; pa.WT[2] = WTv; pa.WT[3] = WTo;
    pa.out_zero = (float*)d_out;
    prep_kernel<<<dim3(2048, 1, 8), 256, 0, stream>>>(pa);

    const float QSCALE = 0.0450842200f;  // log2(e) / 32

    GemmArgs qkv;
    qkv.X[0] = qb_;  qkv.X[1] = kb_;  qkv.X[2] = vb_;
    qkv.WT[0] = WTq; qkv.WT[1] = WTk; qkv.WT[2] = WTv;
    qkv.bias[0] = bq; qkv.bias[1] = bk; qkv.bias[2] = bv;
    qkv.out[0] = Qh;  qkv.out[1] = Kh;  qkv.out[2] = Vt;
    qkv.layout[0] = 0; qkv.layout[1] = 0; qkv.layout[2] = 1;
    qkv.esc[0] = QSCALE; qkv.esc[1] = 1.0f; qkv.esc[2] = 1.0f;
    gemm_bf16_kernel<<<dim3(8, 32, 3), 256, 0, stream>>>(qkv);

    flash_attn_kernel<<<dim3(8, 16, 4), 256, 0, stream>>>(Qh, Kh, Vt, ctx);

    gemm_splitk_kernel<<<dim3(8, 32, 2), 256, 0, stream>>>(
        ctx, WTo, bo, (float*)d_out);
}